// Round 11
// baseline (825.135 us; speedup 1.0000x reference)
//
#include <hip/hip_runtime.h>
#include <hip/hip_bf16.h>
#include <cmath>

// ---------------------------------------------------------------------------
// Workspace layout (float offsets). ~153 MB footprint (unchanged).
// Lifetime aliasing:
//   [0,12.85M): Y1 -> Y3N -> (after gauss_pool2) bf16 weight buffers
//   [12.85M,25.7M): Y1 -> Y2BF/WT2 -> ROIbf -> O1bf/HG2/ES2/ED2/O2
//   [25.7M,32.1M): Y2 -> HG1 + ES1/ED1
//   [32.1M,35.3M): Y4N -> H1b + H2b
// ---------------------------------------------------------------------------
constexpr long Y1_F    = 0;          // 4x128x224x224 = 25,690,112
constexpr long Y3N_F   = 0;          // 50176x256     = 12,845,056 (NHWC f32)
constexpr long WM2B_F  = 0;          // 256x256 bf16   (after Y3N dead)
constexpr long WG1B_F  = 65536;      // 1024x256 bf16  = 131,072 floats
constexpr long WG2B_F  = 589824;     // 256x1024 bf16  = 131,072 floats
constexpr long ROI_F   = 12845056;   // 4096x3136 bf16 = 6,422,528 floats
constexpr long Y2BF_F  = 12845056;   // 4x12544x128 bf16 (stage2 only)
constexpr long WT2_F   = 16056320;   // 256x1152 bf16
constexpr long O1_F    = 12845056;   // 4096x1024 bf16 (ROIbf dead by then)
constexpr long HG2_F   = 17039360;   // 4096x256 f32
constexpr long ES2_F   = 18087936;   // 4096
constexpr long ED2_F   = 18092032;   // 4096
constexpr long O2_F    = 18096128;   // 4096x256 f32
constexpr long Y2_F    = 25690112;   // 4x128x112x112 f32 (stage1 out)
constexpr long HG1_F   = 25690112;   // 4096x1024 f32 (Y2 dead)
constexpr long ES1_F   = 29884416;   // 4096x4
constexpr long ED1_F   = 29900800;   // 4096x4
constexpr long Y4N_F   = 32112640;   // 4x3136x256 f32
constexpr long H1_F    = 32112640;   // 4096x256 bf16 (Y4N dead)
constexpr long H2_F    = 33161216;   // 4096x256 bf16
constexpr long Y5N_F   = 35323904;   // 12544x64 f32
constexpr long STATS_F = 36126720;   // 256 doubles (512 floats)
constexpr long CNT_F   = 36127232;   // 4096 ints
constexpr long POS_F   = 36131328;   // 4096 ints
constexpr long OFF_F   = 36135424;   // 4097 ints (pad 4104)
constexpr long EID_F   = 36139528;   // 69632 ints
constexpr long Y5T_F   = 36209160;   // 12544x64 f32 post-BN/ReLU
constexpr long WP_F    = 37011976;   // 256x3136 bf16 permuted w_mlp1
constexpr long P1_F    = 37814792;   // 4096x51
constexpr long P2_F    = 38023688;   // 4096x51  -> end 38,232,584 floats

struct GaussW { float w[25]; };
struct K5     { float k[5]; };

typedef __attribute__((ext_vector_type(8))) short bf16x8;
typedef __attribute__((ext_vector_type(4))) float f32x4;

static __device__ __forceinline__ unsigned short f2bf(float f) {
    unsigned int u = __float_as_uint(f);
    unsigned int r = (u + 0x7fffu + ((u >> 16) & 1u)) >> 16;   // RNE
    return (unsigned short)r;
}

// ---------------------------------------------------------------------------
// conv1: 3->128, 3x3, pad1, 224x224 (NCHW fp32), with FUSED BN-group stats.
// Each block covers exactly one BN group (ocg = channels 8*ocg..8*ocg+7),
// so block-reduce in double + 2 atomicAdds replaces the bn_stats re-read.
// ---------------------------------------------------------------------------
__global__ __launch_bounds__(256) void conv1_kernel(const float* __restrict__ img,
    const float* __restrict__ w, float* __restrict__ out, double* __restrict__ stats) {
    int pb  = blockIdx.x % 196;
    int ocg = (blockIdx.x / 196) % 16;
    int b   = blockIdx.x / (196 * 16);
    int pix = pb * 256 + threadIdx.x;
    int y = pix / 224, x = pix % 224;
    const float* ib = img + (long)b * 3 * 50176;
    float in[27];
#pragma unroll
    for (int c = 0; c < 3; ++c)
#pragma unroll
        for (int dy = 0; dy < 3; ++dy) {
            int yy = y + dy - 1;
            bool oky = (unsigned)yy < 224u;
#pragma unroll
            for (int dx = 0; dx < 3; ++dx) {
                int xx = x + dx - 1;
                bool ok = oky && ((unsigned)xx < 224u);
                in[(c * 3 + dy) * 3 + dx] = ok ? ib[(c * 224 + yy) * 224 + xx] : 0.f;
            }
        }
    const float* wb = w + ocg * 8 * 27;
    float* ob = out + ((long)(b * 128 + ocg * 8)) * 50176 + pix;
    double s = 0.0, ss = 0.0;
#pragma unroll
    for (int o = 0; o < 8; ++o) {
        float a = 0.f;
#pragma unroll
        for (int j = 0; j < 27; ++j) a += in[j] * wb[o * 27 + j];
        ob[(long)o * 50176] = a;
        s += a; ss += (double)a * a;
    }
    __shared__ double sh2[512];
    int t = threadIdx.x;
    sh2[t] = s; sh2[256 + t] = ss;
    __syncthreads();
    for (int st = 128; st > 0; st >>= 1) {
        if (t < st) {
            sh2[t] += sh2[t + st];
            sh2[256 + t] += sh2[256 + t + st];
        }
        __syncthreads();
    }
    if (t == 0) {
        atomicAdd(&stats[ocg * 2], sh2[0]);
        atomicAdd(&stats[ocg * 2 + 1], sh2[256]);
    }
}

// ---------------------------------------------------------------------------
// Stage-1 fused BN+ReLU + SEPARABLE Gaussian pool (NCHW).
// R10 profile: 25-tap version was L2-BW-bound (2.57 GB cache traffic, 115us).
// Separable: horizontal 5-tap (BN+ReLU fused) -> LDS hbuf, vertical 5-tap.
// Block = (b, c, 8-output-row tile); grid = 4*128*14 = 7168; LDS 8.5 KB.
// Zero-padding semantics identical to skip-OOB (taps contribute 0).
// ---------------------------------------------------------------------------
__global__ __launch_bounds__(256) void gauss_pool1_sep(const float* __restrict__ in,
    float* __restrict__ out, const double* __restrict__ stats,
    const float* __restrict__ gamma, const float* __restrict__ beta, K5 kk) {
    __shared__ float hbuf[19 * 112];
    int blk = blockIdx.x;
    int tile = blk % 14;
    int c = (blk / 14) % 128;
    int b = blk / (14 * 128);
    int t = threadIdx.x;
    int g = c >> 3;
    double mean = stats[g * 2] * (1.0 / 1605632.0);
    double var  = stats[g * 2 + 1] * (1.0 / 1605632.0) - mean * mean;
    float rs = rsqrtf((float)var + 1e-5f);
    float sc = gamma[g] * rs;
    float sh = beta[g] - (float)mean * sc;
    const float* ib = in + ((long)(b * 128 + c)) * 50176;
    int y0 = tile * 16 - 2;              // first global input row of this tile
    for (int i = t; i < 19 * 112; i += 256) {
        int yl = i / 112, ox = i % 112;
        int yy = y0 + yl;
        float acc = 0.f;
        if ((unsigned)yy < 224u) {
            const float* row = ib + yy * 224;
            int xb = 2 * ox - 2;
#pragma unroll
            for (int dx = 0; dx < 5; ++dx) {
                int xx = xb + dx;
                if ((unsigned)xx < 224u)
                    acc += kk.k[dx] * fmaxf(row[xx] * sc + sh, 0.f);
            }
        }
        hbuf[i] = acc;
    }
    __syncthreads();
    float* ob = out + ((long)(b * 128 + c)) * 12544 + (tile * 8) * 112;
    for (int i = t; i < 8 * 112; i += 256) {
        int oyl = i / 112, ox = i % 112;
        float acc = 0.f;
#pragma unroll
        for (int dy = 0; dy < 5; ++dy)
            acc += kk.k[dy] * hbuf[(2 * oyl + dy) * 112 + ox];
        ob[oyl * 112 + ox] = acc;
    }
}

// ---------------------------------------------------------------------------
// Y2 NCHW f32 -> NHWC bf16 (LDS tiled transpose)
// ---------------------------------------------------------------------------
__global__ __launch_bounds__(256) void nchw2nhwc_bf16(const float* __restrict__ in,
    unsigned short* __restrict__ out) {
    __shared__ float tile[128][65];
    int blk = blockIdx.x;
    int b = blk / 196, p0 = (blk % 196) * 64;
    int t = threadIdx.x;
#pragma unroll 4
    for (int i = 0; i < 32; ++i) {
        int idx = i * 256 + t; int c = idx >> 6; int p = idx & 63;
        tile[c][p] = in[((long)(b * 128 + c)) * 12544 + p0 + p];
    }
    __syncthreads();
#pragma unroll 4
    for (int i = 0; i < 32; ++i) {
        int idx = i * 256 + t; int p = idx >> 7; int c = idx & 127;
        out[((long)(b * 12544) + p0 + p) * 128 + c] = f2bf(tile[c][p]);
    }
}

// ---------------------------------------------------------------------------
// w2 [256][128][3][3] f32 -> Wt [256][k=(dy*3+dx)*128+c] bf16
// ---------------------------------------------------------------------------
__global__ __launch_bounds__(256) void wt2_kernel(const float* __restrict__ w,
    unsigned short* __restrict__ out) {
    int i = blockIdx.x * 256 + threadIdx.x;
    int o = i / 1152, k = i % 1152;
    int dydx = k >> 7, c = k & 127;
    out[i] = f2bf(w[(o * 128 + c) * 9 + dydx]);
}

// ---------------------------------------------------------------------------
// generic f32 -> bf16 cast
// ---------------------------------------------------------------------------
__global__ __launch_bounds__(256) void castbf_kernel(const float* __restrict__ src,
    unsigned short* __restrict__ dst, int n) {
    int i = blockIdx.x * 256 + threadIdx.x;
    if (i < n) dst[i] = f2bf(src[i]);
}

// ---------------------------------------------------------------------------
// conv2 as implicit MFMA GEMM: C[50176][256] = patches(X) @ Wt^T
// 128x128 tile, BK=32, 4 waves, XOR-swizzled LDS. grid = dim3(392, 2)
// ---------------------------------------------------------------------------
__global__ __launch_bounds__(256) void conv2_mfma(
    const unsigned short* __restrict__ X,    // [4][12544][128] bf16
    const unsigned short* __restrict__ Wt,   // [256][1152] bf16
    float* __restrict__ out) {               // [50176][256] f32 (NHWC)
    __shared__ __align__(16) short As[4096];
    __shared__ __align__(16) short Bs[4096];
    const int t = threadIdx.x;
    const int m0 = blockIdx.x * 128;
    const int n0 = blockIdx.y * 128;
    const int b  = m0 / 12544;
    const int pb = m0 % 12544;

    const int rA0 = t >> 2, rA1 = 64 + (t >> 2), cs = t & 3;
    const int p0 = pb + rA0, p1 = pb + rA1;
    const int y0 = p0 / 112, x0 = p0 % 112;
    const int y1 = p1 / 112, x1 = p1 % 112;
    short* aw0 = &As[rA0 * 32 + ((cs ^ ((rA0 >> 1) & 3)) * 8)];
    short* aw1 = &As[rA1 * 32 + ((cs ^ ((rA1 >> 1) & 3)) * 8)];
    short* bw0 = &Bs[rA0 * 32 + ((cs ^ ((rA0 >> 1) & 3)) * 8)];
    short* bw1 = &Bs[rA1 * 32 + ((cs ^ ((rA1 >> 1) & 3)) * 8)];
    const unsigned short* a0p = X + ((long)b * 12544 + p0) * 128 + cs * 8;
    const unsigned short* a1p = X + ((long)b * 12544 + p1) * 128 + cs * 8;
    const unsigned short* b0p = Wt + (long)(n0 + rA0) * 1152 + cs * 8;
    const unsigned short* b1p = Wt + (long)(n0 + rA1) * 1152 + cs * 8;

    const int lane = t & 63, wid = t >> 6;
    const int wr = wid >> 1, wc = wid & 1;
    const int fr = lane & 15, fc = lane >> 4;
    int ra[4], rb[4];
#pragma unroll
    for (int i = 0; i < 4; ++i) {
        int r = wr * 64 + i * 16 + fr;
        ra[i] = r * 32 + ((fc ^ ((r >> 1) & 3)) * 8);
        int rn = wc * 64 + i * 16 + fr;
        rb[i] = rn * 32 + ((fc ^ ((rn >> 1) & 3)) * 8);
    }
    f32x4 acc[4][4];
#pragma unroll
    for (int i = 0; i < 4; ++i)
#pragma unroll
        for (int j = 0; j < 4; ++j) acc[i][j] = (f32x4){0.f, 0.f, 0.f, 0.f};

    uint4 av0, av1, bv0, bv1;
    {
        int yy0 = y0 - 1, xx0 = x0 - 1, yy1 = y1 - 1, xx1 = x1 - 1;
        const int off = (-112 - 1) * 128;
        av0 = ((unsigned)yy0 < 112u && (unsigned)xx0 < 112u) ? *(const uint4*)(a0p + off) : make_uint4(0, 0, 0, 0);
        av1 = ((unsigned)yy1 < 112u && (unsigned)xx1 < 112u) ? *(const uint4*)(a1p + off) : make_uint4(0, 0, 0, 0);
        bv0 = *(const uint4*)(b0p);
        bv1 = *(const uint4*)(b1p);
    }
    for (int step = 0; step < 36; ++step) {
        __syncthreads();
        *(uint4*)aw0 = av0; *(uint4*)aw1 = av1;
        *(uint4*)bw0 = bv0; *(uint4*)bw1 = bv1;
        __syncthreads();
        if (step < 35) {
            int k0 = (step + 1) * 32;
            int dydx = k0 >> 7, coff = k0 & 127;
            int dy = dydx / 3 - 1, dx = dydx % 3 - 1;
            int off = (dy * 112 + dx) * 128 + coff;
            int yy0 = y0 + dy, xx0 = x0 + dx, yy1 = y1 + dy, xx1 = x1 + dx;
            av0 = ((unsigned)yy0 < 112u && (unsigned)xx0 < 112u) ? *(const uint4*)(a0p + off) : make_uint4(0, 0, 0, 0);
            av1 = ((unsigned)yy1 < 112u && (unsigned)xx1 < 112u) ? *(const uint4*)(a1p + off) : make_uint4(0, 0, 0, 0);
            bv0 = *(const uint4*)(b0p + k0);
            bv1 = *(const uint4*)(b1p + k0);
        }
        bf16x8 af[4], bfr[4];
#pragma unroll
        for (int i = 0; i < 4; ++i) {
            af[i]  = *(const bf16x8*)&As[ra[i]];
            bfr[i] = *(const bf16x8*)&Bs[rb[i]];
        }
#pragma unroll
        for (int i = 0; i < 4; ++i)
#pragma unroll
            for (int j = 0; j < 4; ++j)
                acc[i][j] = __builtin_amdgcn_mfma_f32_16x16x32_bf16(af[i], bfr[j], acc[i][j], 0, 0, 0);
    }
#pragma unroll
    for (int i = 0; i < 4; ++i) {
        int rbase = m0 + wr * 64 + i * 16 + fc * 4;
#pragma unroll
        for (int j = 0; j < 4; ++j) {
            int col = n0 + wc * 64 + j * 16 + fr;
#pragma unroll
            for (int r2 = 0; r2 < 4; ++r2)
                out[(long)(rbase + r2) * 256 + col] = acc[i][j][r2];
        }
    }
}

// ---------------------------------------------------------------------------
// Generic bf16 MFMA GEMM: C[M,N] = act(A[M,K] @ B[N,K]^T + bias)
// Same structure as conv2_mfma. M%128==0, N%128==0, K%32==0.
// OUTBF: write bf16 to Cb; else f32 to Cf. grid = dim3(M/128, N/128)
// ---------------------------------------------------------------------------
template <int RELU, int OUTBF>
__global__ __launch_bounds__(256) void bgemm_kernel(
    const unsigned short* __restrict__ A,    // [M][K] bf16
    const unsigned short* __restrict__ B,    // [N][K] bf16
    const float* __restrict__ bias,
    float* __restrict__ Cf, unsigned short* __restrict__ Cb,
    int M, int N, int K) {
    __shared__ __align__(16) short As[4096];
    __shared__ __align__(16) short Bs[4096];
    const int t = threadIdx.x;
    const int m0 = blockIdx.x * 128;
    const int n0 = blockIdx.y * 128;
    const int rA0 = t >> 2, rA1 = 64 + (t >> 2), cs = t & 3;
    short* aw0 = &As[rA0 * 32 + ((cs ^ ((rA0 >> 1) & 3)) * 8)];
    short* aw1 = &As[rA1 * 32 + ((cs ^ ((rA1 >> 1) & 3)) * 8)];
    short* bw0 = &Bs[rA0 * 32 + ((cs ^ ((rA0 >> 1) & 3)) * 8)];
    short* bw1 = &Bs[rA1 * 32 + ((cs ^ ((rA1 >> 1) & 3)) * 8)];
    const unsigned short* a0p = A + (long)(m0 + rA0) * K + cs * 8;
    const unsigned short* a1p = A + (long)(m0 + rA1) * K + cs * 8;
    const unsigned short* b0p = B + (long)(n0 + rA0) * K + cs * 8;
    const unsigned short* b1p = B + (long)(n0 + rA1) * K + cs * 8;

    const int lane = t & 63, wid = t >> 6;
    const int wr = wid >> 1, wc = wid & 1;
    const int fr = lane & 15, fc = lane >> 4;
    int ra[4], rb[4];
#pragma unroll
    for (int i = 0; i < 4; ++i) {
        int r = wr * 64 + i * 16 + fr;
        ra[i] = r * 32 + ((fc ^ ((r >> 1) & 3)) * 8);
        int rn = wc * 64 + i * 16 + fr;
        rb[i] = rn * 32 + ((fc ^ ((rn >> 1) & 3)) * 8);
    }
    f32x4 acc[4][4];
#pragma unroll
    for (int i = 0; i < 4; ++i)
#pragma unroll
        for (int j = 0; j < 4; ++j) acc[i][j] = (f32x4){0.f, 0.f, 0.f, 0.f};

    uint4 av0 = *(const uint4*)(a0p);
    uint4 av1 = *(const uint4*)(a1p);
    uint4 bv0 = *(const uint4*)(b0p);
    uint4 bv1 = *(const uint4*)(b1p);
    const int steps = K >> 5;
    for (int step = 0; step < steps; ++step) {
        __syncthreads();
        *(uint4*)aw0 = av0; *(uint4*)aw1 = av1;
        *(uint4*)bw0 = bv0; *(uint4*)bw1 = bv1;
        __syncthreads();
        if (step < steps - 1) {
            int k0 = (step + 1) * 32;
            av0 = *(const uint4*)(a0p + k0);
            av1 = *(const uint4*)(a1p + k0);
            bv0 = *(const uint4*)(b0p + k0);
            bv1 = *(const uint4*)(b1p + k0);
        }
        bf16x8 af[4], bfr[4];
#pragma unroll
        for (int i = 0; i < 4; ++i) {
            af[i]  = *(const bf16x8*)&As[ra[i]];
            bfr[i] = *(const bf16x8*)&Bs[rb[i]];
        }
#pragma unroll
        for (int i = 0; i < 4; ++i)
#pragma unroll
            for (int j = 0; j < 4; ++j)
                acc[i][j] = __builtin_amdgcn_mfma_f32_16x16x32_bf16(af[i], bfr[j], acc[i][j], 0, 0, 0);
    }
#pragma unroll
    for (int i = 0; i < 4; ++i) {
        int rbase = m0 + wr * 64 + i * 16 + fc * 4;
#pragma unroll
        for (int j = 0; j < 4; ++j) {
            int col = n0 + wc * 64 + j * 16 + fr;
            float bv = bias ? bias[col] : 0.f;
#pragma unroll
            for (int r2 = 0; r2 < 4; ++r2) {
                float v = acc[i][j][r2] + bv;
                if (RELU) v = fmaxf(v, 0.f);
                if (OUTBF) Cb[(long)(rbase + r2) * N + col] = f2bf(v);
                else       Cf[(long)(rbase + r2) * N + col] = v;
            }
        }
    }
}

// ---------------------------------------------------------------------------
// BN stats over NHWC [50176][256], 32 groups of 8 channels.
// 784 blocks x 64 pixels.
// ---------------------------------------------------------------------------
__global__ __launch_bounds__(256) void bn_stats2_nhwc(const float* __restrict__ x,
    double* __restrict__ stats) {
    int t = threadIdx.x;
    long base = (long)blockIdx.x * 64 * 256;
    double s = 0.0, ss = 0.0;
    for (int p = 0; p < 64; ++p) {
        float v = x[base + p * 256 + t];
        s += v; ss += (double)v * v;
    }
    __shared__ double sh[512];
    sh[t] = s; sh[256 + t] = ss;
    __syncthreads();
    if (t < 32) {
        double gs = 0.0, gss = 0.0;
#pragma unroll
        for (int j = 0; j < 8; ++j) { gs += sh[8 * t + j]; gss += sh[256 + 8 * t + j]; }
        atomicAdd(&stats[t * 2], gs);
        atomicAdd(&stats[t * 2 + 1], gss);
    }
}

// ---------------------------------------------------------------------------
// Stage-2 fused BN+ReLU+Gaussian pool on NHWC. One output pixel per block.
// ---------------------------------------------------------------------------
__global__ __launch_bounds__(256) void gauss_pool2_nhwc(const float* __restrict__ in,
    float* __restrict__ out, const double* __restrict__ stats,
    const float* __restrict__ gamma, const float* __restrict__ beta, GaussW gw) {
    int t = threadIdx.x;
    int g = t >> 3;
    double mean = stats[g * 2] * (1.0 / 401408.0);
    double var  = stats[g * 2 + 1] * (1.0 / 401408.0) - mean * mean;
    float rs = rsqrtf((float)var + 1e-5f);
    float sc = gamma[g] * rs;
    float shf = beta[g] - (float)mean * sc;
    int op = blockIdx.x;                 // b*3136 + oy*56 + ox
    int b = op / 3136, r = op % 3136;
    int oy = r / 56, ox = r % 56;
    float acc = 0.f;
#pragma unroll
    for (int dy = 0; dy < 5; ++dy) {
        int yy = 2 * oy + dy - 2;
        if ((unsigned)yy >= 112u) continue;
#pragma unroll
        for (int dx = 0; dx < 5; ++dx) {
            int xx = 2 * ox + dx - 2;
            if ((unsigned)xx >= 112u) continue;
            float v = in[(((long)b * 12544) + yy * 112 + xx) * 256 + t];
            v = fmaxf(v * sc + shf, 0.f);
            acc += v * gw.w[dy * 5 + dx];
        }
    }
    out[(long)op * 256 + t] = acc;
}

// ---------------------------------------------------------------------------
// BN stats over NHWC [12544][64]. 49 blocks.
// ---------------------------------------------------------------------------
__global__ __launch_bounds__(256) void bn_stats3_nhwc(const float* __restrict__ x,
    double* __restrict__ stats) {
    int t = threadIdx.x, c = t & 63, pr = t >> 6;
    long base = (long)blockIdx.x * 256 * 64;
    double s = 0.0, ss = 0.0;
    for (int p = pr; p < 256; p += 4) {
        float v = x[base + p * 64 + c];
        s += v; ss += (double)v * v;
    }
    __shared__ double sh[512];
    sh[t] = s; sh[256 + t] = ss;
    __syncthreads();
    if (t < 64) {
        double gs  = sh[t] + sh[64 + t] + sh[128 + t] + sh[192 + t];
        double gss = sh[256 + t] + sh[320 + t] + sh[384 + t] + sh[448 + t];
        atomicAdd(&stats[t * 2], gs);
        atomicAdd(&stats[t * 2 + 1], gss);
    }
}

// ---------------------------------------------------------------------------
// BN+ReLU elementwise on NHWC [12544][64]. 3136 blocks.
// ---------------------------------------------------------------------------
__global__ __launch_bounds__(256) void bnrelu3_nhwc(const float* __restrict__ in,
    float* __restrict__ out, const double* __restrict__ stats,
    const float* __restrict__ gamma, const float* __restrict__ beta) {
    int i = blockIdx.x * 256 + threadIdx.x;
    int c = i & 63;
    double mean = stats[c * 2] * (1.0 / 12544.0);
    double var  = stats[c * 2 + 1] * (1.0 / 12544.0) - mean * mean;
    float rs = rsqrtf((float)var + 1e-5f);
    float sc = gamma[c] * rs;
    float sh = beta[c] - (float)mean * sc;
    out[i] = fmaxf(in[i] * sc + sh, 0.f);
}

// ---------------------------------------------------------------------------
// permute w_mlp1 to bf16: wp[o, p*64+c] = bf(w[o, c*49+p])
// ---------------------------------------------------------------------------
__global__ __launch_bounds__(256) void wperm_kernel(const float* __restrict__ w,
    unsigned short* __restrict__ wp) {
    int gi = blockIdx.x * 256 + threadIdx.x;
    int o = gi / 3136, k = gi % 3136;
    int c = k & 63, p = k >> 6;
    wp[gi] = f2bf(w[(long)o * 3136 + c * 49 + p]);
}

// ---------------------------------------------------------------------------
// ROI align on NHWC feature (4,56,56,64) -> bf16 rows of A
// ---------------------------------------------------------------------------
__global__ __launch_bounds__(256) void roi_kernel(const float* __restrict__ fp,
    const float* __restrict__ boxes, const int* __restrict__ bidx,
    unsigned short* __restrict__ roi) {
    int gi = blockIdx.x * 256 + threadIdx.x;
    int c = gi & 63;
    int rest = gi >> 6;
    int p = rest % 49;
    int nb = rest / 49;
    int oy = p / 7, ox = p % 7;
    int b = bidx[nb];
    float x1 = boxes[nb * 4 + 0] * 0.25f - 0.5f;
    float y1 = boxes[nb * 4 + 1] * 0.25f - 0.5f;
    float x2 = boxes[nb * 4 + 2] * 0.25f - 0.5f;
    float y2 = boxes[nb * 4 + 3] * 0.25f - 0.5f;
    float bw = (x2 - x1) / 7.0f;
    float bh = (y2 - y1) / 7.0f;
    const float* fb = fp + (long)b * 3136 * 64;
    float acc = 0.f;
#pragma unroll
    for (int iy = 0; iy < 2; ++iy) {
        float gy = ((float)(oy * 2 + iy) + 0.5f) / 2.0f;
        float ys = y1 + bh * gy;
        bool vy = (ys >= -1.0f) && (ys <= 56.0f);
        float yc = fminf(fmaxf(ys, 0.f), 55.f);
        float y0f = floorf(yc);
        int y0 = (int)y0f;
        int yp = min(y0 + 1, 55);
        float ly = yc - y0f, hy = 1.f - ly;
#pragma unroll
        for (int ix = 0; ix < 2; ++ix) {
            float gx = ((float)(ox * 2 + ix) + 0.5f) / 2.0f;
            float xs = x1 + bw * gx;
            bool vx = (xs >= -1.0f) && (xs <= 56.0f);
            float xc = fminf(fmaxf(xs, 0.f), 55.f);
            float x0f = floorf(xc);
            int x0 = (int)x0f;
            int xp = min(x0 + 1, 55);
            float lx = xc - x0f, hx = 1.f - lx;
            float v00 = fb[(y0 * 56 + x0) * 64 + c];
            float v01 = fb[(y0 * 56 + xp) * 64 + c];
            float v10 = fb[(yp * 56 + x0) * 64 + c];
            float v11 = fb[(yp * 56 + xp) * 64 + c];
            float v = v00 * (hy * hx) + v01 * (hy * lx) + v10 * (ly * hx) + v11 * (ly * lx);
            acc += (vy && vx) ? v : 0.f;
        }
    }
    roi[(long)rest * 64 + c] = f2bf(acc * 0.25f);
}

// ---------------------------------------------------------------------------
// fp32 SIMT GEMM (small N: conv3, heads). C = act(A @ W^T + bias)
// ---------------------------------------------------------------------------
__global__ __launch_bounds__(256) void gemm_kernel(const float* __restrict__ A,
    const float* __restrict__ W, const float* __restrict__ bias,
    float* __restrict__ C, int M, int N, int K, int ldw, int relu) {
    __shared__ float As[16][68];
    __shared__ float Ws[16][68];
    const int t = threadIdx.x;
    const int m0 = blockIdx.y * 64, n0 = blockIdx.x * 64;
    const int tx = t & 15, ty = t >> 4;
    const int lm = t >> 2, lk = (t & 3) * 4;
    float acc[4][4] = {};
    for (int k0 = 0; k0 < K; k0 += 16) {
        float4 av = *(const float4*)(A + (long)(m0 + lm) * K + (k0 + lk));
        float4 wv = make_float4(0.f, 0.f, 0.f, 0.f);
        if (n0 + lm < N) wv = *(const float4*)(W + (long)(n0 + lm) * ldw + (k0 + lk));
        As[lk + 0][lm] = av.x; As[lk + 1][lm] = av.y; As[lk + 2][lm] = av.z; As[lk + 3][lm] = av.w;
        Ws[lk + 0][lm] = wv.x; Ws[lk + 1][lm] = wv.y; Ws[lk + 2][lm] = wv.z; Ws[lk + 3][lm] = wv.w;
        __syncthreads();
#pragma unroll
        for (int k = 0; k < 16; ++k) {
            float4 a = *(const float4*)&As[k][ty * 4];
            float4 bv = *(const float4*)&Ws[k][tx * 4];
            acc[0][0] += a.x * bv.x; acc[0][1] += a.x * bv.y; acc[0][2] += a.x * bv.z; acc[0][3] += a.x * bv.w;
            acc[1][0] += a.y * bv.x; acc[1][1] += a.y * bv.y; acc[1][2] += a.y * bv.z; acc[1][3] += a.y * bv.w;
            acc[2][0] += a.z * bv.x; acc[2][1] += a.z * bv.y; acc[2][2] += a.z * bv.z; acc[2][3] += a.z * bv.w;
            acc[3][0] += a.w * bv.x; acc[3][1] += a.w * bv.y; acc[3][2] += a.w * bv.z; acc[3][3] += a.w * bv.w;
        }
        __syncthreads();
    }
#pragma unroll
    for (int i = 0; i < 4; ++i) {
        int m = m0 + ty * 4 + i;
#pragma unroll
        for (int j = 0; j < 4; ++j) {
            int n = n0 + tx * 4 + j;
            if (n < N) {
                float v = acc[i][j] + (bias ? bias[n] : 0.f);
                if (relu) v = fmaxf(v, 0.f);
                C[(long)m * N + n] = v;
            }
        }
    }
}

// ---------------------------------------------------------------------------
// attention dots
// ---------------------------------------------------------------------------
__global__ __launch_bounds__(256) void attn_dots_kernel(const float* __restrict__ h,
    const float* __restrict__ a_s, const float* __restrict__ a_d,
    float* __restrict__ es, float* __restrict__ ed, int heads) {
    int wid = (blockIdx.x * 256 + threadIdx.x) >> 6;
    int lane = threadIdx.x & 63;
    int hd = wid % heads;
    float4 hv = *(const float4*)&h[(long)wid * 256 + lane * 4];
    float4 av = *(const float4*)&a_s[hd * 256 + lane * 4];
    float4 dv = *(const float4*)&a_d[hd * 256 + lane * 4];
    float ps = hv.x * av.x + hv.y * av.y + hv.z * av.z + hv.w * av.w;
    float pd = hv.x * dv.x + hv.y * dv.y + hv.z * dv.z + hv.w * dv.w;
    for (int o = 32; o > 0; o >>= 1) {
        ps += __shfl_down(ps, o, 64);
        pd += __shfl_down(pd, o, 64);
    }
    if (lane == 0) { es[wid] = ps; ed[wid] = pd; }
}

// ---------------------------------------------------------------------------
// CSR build over dst
// ---------------------------------------------------------------------------
__global__ __launch_bounds__(256) void edge_count_kernel(const int* __restrict__ ei,
    int* __restrict__ cnt, int E, int tot) {
    int k = blockIdx.x * 256 + threadIdx.x;
    if (k >= tot) return;
    int d = (k < E) ? ei[E + k] : (k - E);
    atomicAdd(&cnt[d], 1);
}

__global__ __launch_bounds__(1024) void scan_kernel(const int* __restrict__ cnt,
    int* __restrict__ off) {
    __shared__ int sh[1024];
    int t = threadIdx.x;
    int base = t * 4;
    int c0 = cnt[base], c1 = cnt[base + 1], c2 = cnt[base + 2], c3 = cnt[base + 3];
    sh[t] = c0 + c1 + c2 + c3;
    __syncthreads();
    for (int d = 1; d < 1024; d <<= 1) {
        int v = (t >= d) ? sh[t - d] : 0;
        __syncthreads();
        sh[t] += v;
        __syncthreads();
    }
    int excl = (t == 0) ? 0 : sh[t - 1];
    off[base] = excl;
    off[base + 1] = excl + c0;
    off[base + 2] = excl + c0 + c1;
    off[base + 3] = excl + c0 + c1 + c2;
    if (t == 1023) off[4096] = sh[1023];
}

__global__ __launch_bounds__(256) void edge_scatter_kernel(const int* __restrict__ ei,
    const int* __restrict__ off, int* __restrict__ pos, int* __restrict__ eid,
    int E, int tot) {
    int k = blockIdx.x * 256 + threadIdx.x;
    if (k >= tot) return;
    int d = (k < E) ? ei[E + k] : (k - E);
    int p = atomicAdd(&pos[d], 1);
    eid[off[d] + p] = k;
}

// ---------------------------------------------------------------------------
// GAT aggregation. OUTBF: write bf16 (feeds next bgemm) else f32.
// ---------------------------------------------------------------------------
template <int HEADS, int OUTBF>
__global__ __launch_bounds__(256) void gat_aggregate_kernel(const float* __restrict__ h,
    const float* __restrict__ es, const float* __restrict__ ed,
    const int* __restrict__ off, const int* __restrict__ eid,
    const int* __restrict__ ei, const float* __restrict__ bias,
    void* __restrict__ outp, int E) {
    int n = blockIdx.x;
    int t = threadIdx.x;
    int o0 = off[n];
    int deg = off[n + 1] - o0;
    if (deg > 1024) deg = 1024;
    __shared__ float ew[4096];
    __shared__ int   srcs[1024];
    __shared__ float mden[2 * HEADS];
    for (int i = t; i < deg; i += 256) {
        int k = eid[o0 + i];
        int s = (k < E) ? ei[k] : (k - E);
        srcs[i] = s;
#pragma unroll
        for (int hd = 0; hd < HEADS; ++hd) {
            float e = es[s * HEADS + hd] + ed[n * HEADS + hd];
            e = (e >= 0.f) ? e : 0.2f * e;
            ew[i * HEADS + hd] = e;
        }
    }
    __syncthreads();
    if (t < HEADS) {
        float m = -1e30f;
        for (int i = 0; i < deg; ++i) m = fmaxf(m, ew[i * HEADS + t]);
        float den = 0.f;
        for (int i = 0; i < deg; ++i) den += expf(ew[i * HEADS + t] - m);
        mden[t] = m;
        mden[HEADS + t] = den + 1e-16f;
    }
    __syncthreads();
    for (int idx = t; idx < deg * HEADS; idx += 256) {
        int hd = idx % HEADS;
        ew[idx] = expf(ew[idx] - mden[hd]) / mden[HEADS + hd];
    }
    __syncthreads();
    float acc[HEADS];
#pragma unroll
    for (int hd = 0; hd < HEADS; ++hd) acc[hd] = 0.f;
    for (int i = 0; i < deg; ++i) {
        int s = srcs[i];
        const float* hr = &h[(long)s * HEADS * 256];
#pragma unroll
        for (int hd = 0; hd < HEADS; ++hd)
            acc[hd] += ew[i * HEADS + hd] * hr[hd * 256 + t];
    }
#pragma unroll
    for (int hd = 0; hd < HEADS; ++hd) {
        float v = acc[hd] + bias[hd * 256 + t];
        long oi = ((long)n * HEADS + hd) * 256 + t;
        if (OUTBF) ((unsigned short*)outp)[oi] = f2bf(v);
        else       ((float*)outp)[oi] = v;
    }
}

// ---------------------------------------------------------------------------
// rel_logits[e,o] = P1[src_e,o] + P2[dst_e,o] + b_rel[o]
// ---------------------------------------------------------------------------
__global__ __launch_bounds__(256) void rel_scatter_kernel(const float* __restrict__ P1,
    const float* __restrict__ P2, const float* __restrict__ brel,
    const int* __restrict__ ei, float* __restrict__ out, int E) {
    int gi = blockIdx.x * 256 + threadIdx.x;
    int o = gi & 63;
    int e = gi >> 6;
    if (o >= 51 || e >= E) return;
    int s = ei[e], d = ei[E + e];
    out[(long)e * 51 + o] = P1[(long)s * 51 + o] + P2[(long)d * 51 + o] + brel[o];
}

// ---------------------------------------------------------------------------
extern "C" void kernel_launch(void* const* d_in, const int* in_sizes, int n_in,
                              void* d_out, int out_size, void* d_ws, size_t ws_size,
                              hipStream_t stream) {
    const float* images = (const float*)d_in[0];
    const float* boxes  = (const float*)d_in[1];
    const int*   bidx   = (const int*)d_in[2];
    const int*   ei     = (const int*)d_in[3];
    const float* w1     = (const float*)d_in[4];
    const float* g1     = (const float*)d_in[5];
    const float* b1     = (const float*)d_in[6];
    const float* w2     = (const float*)d_in[7];
    const float* g2     = (const float*)d_in[8];
    const float* b2     = (const float*)d_in[9];
    const float* w3     = (const float*)d_in[10];
    const float* g3     = (const float*)d_in[11];
    const float* b3     = (const float*)d_in[12];
    const float* wm1    = (const float*)d_in[13];
    const float* bm1    = (const float*)d_in[14];
    const float* wm2    = (const float*)d_in[15];
    const float* bm2    = (const float*)d_in[16];
    const float* wg1    = (const float*)d_in[17];
    const float* as1    = (const float*)d_in[18];
    const float* ad1    = (const float*)d_in[19];
    const float* bias1  = (const float*)d_in[20];
    const float* wg2    = (const float*)d_in[21];
    const float* as2    = (const float*)d_in[22];
    const float* ad2    = (const float*)d_in[23];
    const float* bias2  = (const float*)d_in[24];
    const float* wobj   = (const float*)d_in[25];
    const float* bobj   = (const float*)d_in[26];
    const float* wrel   = (const float*)d_in[27];
    const float* brel   = (const float*)d_in[28];

    float* ws = (float*)d_ws;
    float* out = (float*)d_out;
    const int E = 65536, TOT = 69632;

    float*  Y1   = ws + Y1_F;
    float*  Y2   = ws + Y2_F;
    float*  Y3N  = ws + Y3N_F;
    float*  Y4N  = ws + Y4N_F;
    float*  Y5N  = ws + Y5N_F;
    float*  Y5T  = ws + Y5T_F;
    float*  HG1  = ws + HG1_F;
    float*  ES1  = ws + ES1_F;
    float*  ED1  = ws + ED1_F;
    float*  HG2  = ws + HG2_F;
    float*  ES2  = ws + ES2_F;
    float*  ED2  = ws + ED2_F;
    float*  O2   = ws + O2_F;
    float*  P1   = ws + P1_F;
    float*  P2   = ws + P2_F;
    unsigned short* Y2BF = (unsigned short*)(ws + Y2BF_F);
    unsigned short* WT2  = (unsigned short*)(ws + WT2_F);
    unsigned short* ROIb = (unsigned short*)(ws + ROI_F);
    unsigned short* WPb  = (unsigned short*)(ws + WP_F);
    unsigned short* H1b  = (unsigned short*)(ws + H1_F);
    unsigned short* H2b  = (unsigned short*)(ws + H2_F);
    unsigned short* O1b  = (unsigned short*)(ws + O1_F);
    unsigned short* WM2b = (unsigned short*)(ws + WM2B_F);
    unsigned short* WG1b = (unsigned short*)(ws + WG1B_F);
    unsigned short* WG2b = (unsigned short*)(ws + WG2B_F);
    double* SD  = (double*)(ws + STATS_F);
    int*    CNT = (int*)(ws + CNT_F);
    int*    POS = (int*)(ws + POS_F);
    int*    OFF = (int*)(ws + OFF_F);
    int*    EID = (int*)(ws + EID_F);

    GaussW gw;
    K5 k5;
    {
        float k1[5];
        float s2 = 2.0f * 0.66f * 0.66f;
        for (int i = 0; i < 5; ++i) {
            float r = (float)i - 2.0f;
            k1[i] = expf(-r * r / s2);
        }
        float tot = 0.f;
        for (int i = 0; i < 5; ++i)
            for (int j = 0; j < 5; ++j) { gw.w[i * 5 + j] = k1[i] * k1[j]; tot += gw.w[i * 5 + j]; }
        for (int i = 0; i < 25; ++i) gw.w[i] /= tot;
        float s1 = 0.f;
        for (int i = 0; i < 5; ++i) s1 += k1[i];
        for (int i = 0; i < 5; ++i) k5.k[i] = k1[i] / s1;   // outer(k5,k5) == gw
    }

    // zero stats (512 f) + CNT (4096 i) + POS (4096 i), contiguous
    hipMemsetAsync((char*)d_ws + STATS_F * 4, 0, (512 + 4096 + 4096) * 4, stream);

    // stage 1 (NCHW fp32): conv1 fuses BN-group stats; separable gauss pool
    conv1_kernel<<<12544, 256, 0, stream>>>(images, w1, Y1, SD);
    gauss_pool1_sep<<<4 * 128 * 14, 256, 0, stream>>>(Y1, Y2, SD, g1, b1, k5);
    // stage 2 (MFMA implicit GEMM, NHWC)
    nchw2nhwc_bf16<<<784, 256, 0, stream>>>(Y2, Y2BF);
    wt2_kernel<<<1152, 256, 0, stream>>>(w2, WT2);
    conv2_mfma<<<dim3(392, 2), 256, 0, stream>>>(Y2BF, WT2, Y3N);
    bn_stats2_nhwc<<<784, 256, 0, stream>>>(Y3N, SD + 32);
    gauss_pool2_nhwc<<<12544, 256, 0, stream>>>(Y3N, Y4N, SD + 32, g2, b2, gw);
    // stage 3 (1x1 conv == fp32 GEMM on NHWC)
    gemm_kernel<<<dim3(1, 196), 256, 0, stream>>>(Y4N, w3, nullptr, Y5N, 12544, 64, 256, 256, 0);
    bn_stats3_nhwc<<<49, 256, 0, stream>>>(Y5N, SD + 96);
    bnrelu3_nhwc<<<3136, 256, 0, stream>>>(Y5N, Y5T, SD + 96, g3, b3);
    // bf16 weight prep (in dead Y3N region -> must be after gauss_pool2)
    // w_gat1 (1024x256) and w_gat2 (256x1024) are 262,144 elements each.
    wperm_kernel<<<3136, 256, 0, stream>>>(wm1, WPb);
    castbf_kernel<<<256, 256, 0, stream>>>(wm2, WM2b, 65536);
    castbf_kernel<<<1024, 256, 0, stream>>>(wg1, WG1b, 262144);
    castbf_kernel<<<1024, 256, 0, stream>>>(wg2, WG2b, 262144);
    // ROI align + MLP (bf16 MFMA)
    roi_kernel<<<50176, 256, 0, stream>>>(Y5T, boxes, bidx, ROIb);
    bgemm_kernel<1, 1><<<dim3(32, 2), 256, 0, stream>>>(ROIb, WPb, bm1, nullptr, H1b, 4096, 256, 3136);
    bgemm_kernel<1, 1><<<dim3(32, 2), 256, 0, stream>>>(H1b, WM2b, bm2, nullptr, H2b, 4096, 256, 256);
    // CSR over dst (shared by both GAT layers)
    edge_count_kernel<<<272, 256, 0, stream>>>(ei, CNT, E, TOT);
    scan_kernel<<<1, 1024, 0, stream>>>(CNT, OFF);
    edge_scatter_kernel<<<272, 256, 0, stream>>>(ei, OFF, POS, EID, E, TOT);
    // GAT layer 1 (4 heads, concat)
    bgemm_kernel<0, 0><<<dim3(32, 8), 256, 0, stream>>>(H2b, WG1b, nullptr, HG1, nullptr, 4096, 1024, 256);
    attn_dots_kernel<<<4096, 256, 0, stream>>>(HG1, as1, ad1, ES1, ED1, 4);
    gat_aggregate_kernel<4, 1><<<4096, 256, 0, stream>>>(HG1, ES1, ED1, OFF, EID, ei, bias1, O1b, E);
    // GAT layer 2 (1 head)
    bgemm_kernel<0, 0><<<dim3(32, 2), 256, 0, stream>>>(O1b, WG2b, nullptr, HG2, nullptr, 4096, 256, 1024);
    attn_dots_kernel<<<1024, 256, 0, stream>>>(HG2, as2, ad2, ES2, ED2, 1);
    gat_aggregate_kernel<1, 0><<<4096, 256, 0, stream>>>(HG2, ES2, ED2, OFF, EID, ei, bias2, O2, E);
    // heads (fp32, small N)
    gemm_kernel<<<dim3(3, 64), 256, 0, stream>>>(O2, wobj, bobj, out, 4096, 151, 256, 256, 0);
    gemm_kernel<<<dim3(1, 64), 256, 0, stream>>>(O2, wrel, nullptr, P1, 4096, 51, 256, 512, 0);
    gemm_kernel<<<dim3(1, 64), 256, 0, stream>>>(O2, wrel + 256, nullptr, P2, 4096, 51, 256, 512, 0);
    rel_scatter_kernel<<<16384, 256, 0, stream>>>(P1, P2, brel, ei, out + 618496, E);
}

// Round 12
// 743.500 us; speedup vs baseline: 1.1098x; 1.1098x over previous
//
#include <hip/hip_runtime.h>
#include <hip/hip_bf16.h>
#include <cmath>

// ---------------------------------------------------------------------------
// Workspace layout (float offsets). ~153 MB footprint (unchanged).
// ---------------------------------------------------------------------------
constexpr long Y1_F    = 0;          // 4x128x224x224 = 25,690,112
constexpr long Y3N_F   = 0;          // 50176x256     = 12,845,056 (NHWC f32)
constexpr long WM2B_F  = 0;          // 256x256 bf16   (after Y3N dead)
constexpr long WG1B_F  = 65536;      // 1024x256 bf16  = 131,072 floats
constexpr long WG2B_F  = 589824;     // 256x1024 bf16  = 131,072 floats
constexpr long ROI_F   = 12845056;   // 4096x3136 bf16 = 6,422,528 floats
constexpr long Y2BF_F  = 12845056;   // 4x12544x128 bf16 (stage2 only)
constexpr long WT2_F   = 16056320;   // 256x1152 bf16
constexpr long O1_F    = 12845056;   // 4096x1024 bf16 (ROIbf dead by then)
constexpr long HG2_F   = 17039360;   // 4096x256 f32
constexpr long ES2_F   = 18087936;   // 4096
constexpr long ED2_F   = 18092032;   // 4096
constexpr long O2_F    = 18096128;   // 4096x256 f32
constexpr long Y2_F    = 25690112;   // 4x128x112x112 f32 (stage1 out)
constexpr long HG1_F   = 25690112;   // 4096x1024 f32 (Y2 dead)
constexpr long ES1_F   = 29884416;   // 4096x4
constexpr long ED1_F   = 29900800;   // 4096x4
constexpr long Y4N_F   = 32112640;   // 4x3136x256 f32
constexpr long H1_F    = 32112640;   // 4096x256 bf16 (Y4N dead)
constexpr long H2_F    = 33161216;   // 4096x256 bf16
constexpr long Y5N_F   = 35323904;   // 12544x64 f32
constexpr long STATS_F = 36126720;   // 256 doubles (512 floats)
constexpr long CNT_F   = 36127232;   // 4096 ints
constexpr long POS_F   = 36131328;   // 4096 ints
constexpr long OFF_F   = 36135424;   // 4097 ints (pad 4104)
constexpr long EID_F   = 36139528;   // 69632 ints
constexpr long Y5T_F   = 36209160;   // 12544x64 f32 post-BN/ReLU
constexpr long WP_F    = 37011976;   // 256x3136 bf16 permuted w_mlp1
constexpr long P1_F    = 37814792;   // 4096x51
constexpr long P2_F    = 38023688;   // 4096x51  -> end 38,232,584 floats

struct GaussW { float w[25]; };
struct K5     { float k[5]; };

typedef __attribute__((ext_vector_type(8))) short bf16x8;
typedef __attribute__((ext_vector_type(4))) float f32x4;

static __device__ __forceinline__ unsigned short f2bf(float f) {
    unsigned int u = __float_as_uint(f);
    unsigned int r = (u + 0x7fffu + ((u >> 16) & 1u)) >> 16;   // RNE
    return (unsigned short)r;
}

// ---------------------------------------------------------------------------
// conv1: 3->128, 3x3, pad1, 224x224 (NCHW fp32).
// R11 lesson: fusing BN stats here (fp64 atomics + barrier tree) cost ~40us.
// Reverted to the plain R10 version.
// ---------------------------------------------------------------------------
__global__ __launch_bounds__(256) void conv1_kernel(const float* __restrict__ img,
    const float* __restrict__ w, float* __restrict__ out) {
    int pb  = blockIdx.x % 196;
    int ocg = (blockIdx.x / 196) % 16;
    int b   = blockIdx.x / (196 * 16);
    int pix = pb * 256 + threadIdx.x;
    int y = pix / 224, x = pix % 224;
    const float* ib = img + (long)b * 3 * 50176;
    float in[27];
#pragma unroll
    for (int c = 0; c < 3; ++c)
#pragma unroll
        for (int dy = 0; dy < 3; ++dy) {
            int yy = y + dy - 1;
            bool oky = (unsigned)yy < 224u;
#pragma unroll
            for (int dx = 0; dx < 3; ++dx) {
                int xx = x + dx - 1;
                bool ok = oky && ((unsigned)xx < 224u);
                in[(c * 3 + dy) * 3 + dx] = ok ? ib[(c * 224 + yy) * 224 + xx] : 0.f;
            }
        }
    const float* wb = w + ocg * 8 * 27;
    float* ob = out + ((long)(b * 128 + ocg * 8)) * 50176 + pix;
#pragma unroll
    for (int o = 0; o < 8; ++o) {
        float a = 0.f;
#pragma unroll
        for (int j = 0; j < 27; ++j) a += in[j] * wb[o * 27 + j];
        ob[(long)o * 50176] = a;
    }
}

// ---------------------------------------------------------------------------
// BN stats (NCHW, stage 1): per-group sum/sumsq via double atomics
// ---------------------------------------------------------------------------
__global__ __launch_bounds__(256) void bn_stats_kernel(const float* __restrict__ x,
    double* __restrict__ stats, int C, int HW, int fs, int B) {
    int g = blockIdx.y;
    int fsHW = fs * HW;
    double s = 0.0, ss = 0.0;
    for (int b = 0; b < B; ++b) {
        const float* xb = x + ((long)b * C + (long)g * fs) * HW;
        for (int r = blockIdx.x * 256 + threadIdx.x; r < fsHW; r += gridDim.x * 256) {
            float v = xb[r];
            s += v; ss += (double)v * v;
        }
    }
    __shared__ double sh[512];
    sh[threadIdx.x] = s; sh[256 + threadIdx.x] = ss;
    __syncthreads();
    for (int st = 128; st > 0; st >>= 1) {
        if (threadIdx.x < st) {
            sh[threadIdx.x] += sh[threadIdx.x + st];
            sh[256 + threadIdx.x] += sh[256 + threadIdx.x + st];
        }
        __syncthreads();
    }
    if (threadIdx.x == 0) {
        atomicAdd(&stats[g * 2], sh[0]);
        atomicAdd(&stats[g * 2 + 1], sh[256]);
    }
}

// ---------------------------------------------------------------------------
// Stage-1 fused BN+ReLU + SEPARABLE Gaussian pool (NCHW), LDS-staged input.
// R11 deduction: hpass's 5 stride-2 scalar global loads per output made the
// un-staged version ~2.5x read-amplified. Now: coalesced 1x load of the
// 19x224 row tile into LDS (BN+ReLU applied once, OOB rows = 0, matching
// reference's post-ReLU zero padding), then hpass/vpass from LDS.
// LDS: ibuf 17 KB + hbuf 8.5 KB = 25.5 KB. grid = 4*128*14 = 7168.
// ---------------------------------------------------------------------------
__global__ __launch_bounds__(256) void gauss_pool1_sep(const float* __restrict__ in,
    float* __restrict__ out, const double* __restrict__ stats,
    const float* __restrict__ gamma, const float* __restrict__ beta, K5 kk) {
    __shared__ float ibuf[19 * 224];
    __shared__ float hbuf[19 * 112];
    int blk = blockIdx.x;
    int tile = blk % 14;
    int c = (blk / 14) % 128;
    int b = blk / (14 * 128);
    int t = threadIdx.x;
    int g = c >> 3;
    double mean = stats[g * 2] * (1.0 / 1605632.0);
    double var  = stats[g * 2 + 1] * (1.0 / 1605632.0) - mean * mean;
    float rs = rsqrtf((float)var + 1e-5f);
    float sc = gamma[g] * rs;
    float sh = beta[g] - (float)mean * sc;
    const float* ib = in + ((long)(b * 128 + c)) * 50176;
    int y0 = tile * 16 - 2;              // first global input row of this tile
    // stage: BN+ReLU once per element, 0 for OOB rows (post-ReLU zero pad)
    for (int i = t; i < 19 * 224; i += 256) {
        int yl = i / 224, x = i % 224;
        int yy = y0 + yl;
        float v = 0.f;
        if ((unsigned)yy < 224u)
            v = fmaxf(ib[yy * 224 + x] * sc + sh, 0.f);
        ibuf[i] = v;
    }
    __syncthreads();
    // horizontal 5-tap (stride 2), x zero-padded
    for (int i = t; i < 19 * 112; i += 256) {
        int yl = i / 112, ox = i % 112;
        const float* row = &ibuf[yl * 224];
        int xb = 2 * ox - 2;
        float acc = 0.f;
#pragma unroll
        for (int dx = 0; dx < 5; ++dx) {
            int xx = xb + dx;
            if ((unsigned)xx < 224u) acc += kk.k[dx] * row[xx];
        }
        hbuf[i] = acc;
    }
    __syncthreads();
    // vertical 5-tap (stride 2)
    float* ob = out + ((long)(b * 128 + c)) * 12544 + (tile * 8) * 112;
    for (int i = t; i < 8 * 112; i += 256) {
        int oyl = i / 112, ox = i % 112;
        float acc = 0.f;
#pragma unroll
        for (int dy = 0; dy < 5; ++dy)
            acc += kk.k[dy] * hbuf[(2 * oyl + dy) * 112 + ox];
        ob[oyl * 112 + ox] = acc;
    }
}

// ---------------------------------------------------------------------------
// Y2 NCHW f32 -> NHWC bf16 (LDS tiled transpose)
// ---------------------------------------------------------------------------
__global__ __launch_bounds__(256) void nchw2nhwc_bf16(const float* __restrict__ in,
    unsigned short* __restrict__ out) {
    __shared__ float tile[128][65];
    int blk = blockIdx.x;
    int b = blk / 196, p0 = (blk % 196) * 64;
    int t = threadIdx.x;
#pragma unroll 4
    for (int i = 0; i < 32; ++i) {
        int idx = i * 256 + t; int c = idx >> 6; int p = idx & 63;
        tile[c][p] = in[((long)(b * 128 + c)) * 12544 + p0 + p];
    }
    __syncthreads();
#pragma unroll 4
    for (int i = 0; i < 32; ++i) {
        int idx = i * 256 + t; int p = idx >> 7; int c = idx & 127;
        out[((long)(b * 12544) + p0 + p) * 128 + c] = f2bf(tile[c][p]);
    }
}

// ---------------------------------------------------------------------------
// w2 [256][128][3][3] f32 -> Wt [256][k=(dy*3+dx)*128+c] bf16
// ---------------------------------------------------------------------------
__global__ __launch_bounds__(256) void wt2_kernel(const float* __restrict__ w,
    unsigned short* __restrict__ out) {
    int i = blockIdx.x * 256 + threadIdx.x;
    int o = i / 1152, k = i % 1152;
    int dydx = k >> 7, c = k & 127;
    out[i] = f2bf(w[(o * 128 + c) * 9 + dydx]);
}

// ---------------------------------------------------------------------------
// generic f32 -> bf16 cast
// ---------------------------------------------------------------------------
__global__ __launch_bounds__(256) void castbf_kernel(const float* __restrict__ src,
    unsigned short* __restrict__ dst, int n) {
    int i = blockIdx.x * 256 + threadIdx.x;
    if (i < n) dst[i] = f2bf(src[i]);
}

// ---------------------------------------------------------------------------
// conv2 as implicit MFMA GEMM: C[50176][256] = patches(X) @ Wt^T
// 128x128 tile, BK=32, 4 waves, XOR-swizzled LDS. grid = dim3(392, 2)
// ---------------------------------------------------------------------------
__global__ __launch_bounds__(256) void conv2_mfma(
    const unsigned short* __restrict__ X,    // [4][12544][128] bf16
    const unsigned short* __restrict__ Wt,   // [256][1152] bf16
    float* __restrict__ out) {               // [50176][256] f32 (NHWC)
    __shared__ __align__(16) short As[4096];
    __shared__ __align__(16) short Bs[4096];
    const int t = threadIdx.x;
    const int m0 = blockIdx.x * 128;
    const int n0 = blockIdx.y * 128;
    const int b  = m0 / 12544;
    const int pb = m0 % 12544;

    const int rA0 = t >> 2, rA1 = 64 + (t >> 2), cs = t & 3;
    const int p0 = pb + rA0, p1 = pb + rA1;
    const int y0 = p0 / 112, x0 = p0 % 112;
    const int y1 = p1 / 112, x1 = p1 % 112;
    short* aw0 = &As[rA0 * 32 + ((cs ^ ((rA0 >> 1) & 3)) * 8)];
    short* aw1 = &As[rA1 * 32 + ((cs ^ ((rA1 >> 1) & 3)) * 8)];
    short* bw0 = &Bs[rA0 * 32 + ((cs ^ ((rA0 >> 1) & 3)) * 8)];
    short* bw1 = &Bs[rA1 * 32 + ((cs ^ ((rA1 >> 1) & 3)) * 8)];
    const unsigned short* a0p = X + ((long)b * 12544 + p0) * 128 + cs * 8;
    const unsigned short* a1p = X + ((long)b * 12544 + p1) * 128 + cs * 8;
    const unsigned short* b0p = Wt + (long)(n0 + rA0) * 1152 + cs * 8;
    const unsigned short* b1p = Wt + (long)(n0 + rA1) * 1152 + cs * 8;

    const int lane = t & 63, wid = t >> 6;
    const int wr = wid >> 1, wc = wid & 1;
    const int fr = lane & 15, fc = lane >> 4;
    int ra[4], rb[4];
#pragma unroll
    for (int i = 0; i < 4; ++i) {
        int r = wr * 64 + i * 16 + fr;
        ra[i] = r * 32 + ((fc ^ ((r >> 1) & 3)) * 8);
        int rn = wc * 64 + i * 16 + fr;
        rb[i] = rn * 32 + ((fc ^ ((rn >> 1) & 3)) * 8);
    }
    f32x4 acc[4][4];
#pragma unroll
    for (int i = 0; i < 4; ++i)
#pragma unroll
        for (int j = 0; j < 4; ++j) acc[i][j] = (f32x4){0.f, 0.f, 0.f, 0.f};

    uint4 av0, av1, bv0, bv1;
    {
        int yy0 = y0 - 1, xx0 = x0 - 1, yy1 = y1 - 1, xx1 = x1 - 1;
        const int off = (-112 - 1) * 128;
        av0 = ((unsigned)yy0 < 112u && (unsigned)xx0 < 112u) ? *(const uint4*)(a0p + off) : make_uint4(0, 0, 0, 0);
        av1 = ((unsigned)yy1 < 112u && (unsigned)xx1 < 112u) ? *(const uint4*)(a1p + off) : make_uint4(0, 0, 0, 0);
        bv0 = *(const uint4*)(b0p);
        bv1 = *(const uint4*)(b1p);
    }
    for (int step = 0; step < 36; ++step) {
        __syncthreads();
        *(uint4*)aw0 = av0; *(uint4*)aw1 = av1;
        *(uint4*)bw0 = bv0; *(uint4*)bw1 = bv1;
        __syncthreads();
        if (step < 35) {
            int k0 = (step + 1) * 32;
            int dydx = k0 >> 7, coff = k0 & 127;
            int dy = dydx / 3 - 1, dx = dydx % 3 - 1;
            int off = (dy * 112 + dx) * 128 + coff;
            int yy0 = y0 + dy, xx0 = x0 + dx, yy1 = y1 + dy, xx1 = x1 + dx;
            av0 = ((unsigned)yy0 < 112u && (unsigned)xx0 < 112u) ? *(const uint4*)(a0p + off) : make_uint4(0, 0, 0, 0);
            av1 = ((unsigned)yy1 < 112u && (unsigned)xx1 < 112u) ? *(const uint4*)(a1p + off) : make_uint4(0, 0, 0, 0);
            bv0 = *(const uint4*)(b0p + k0);
            bv1 = *(const uint4*)(b1p + k0);
        }
        bf16x8 af[4], bfr[4];
#pragma unroll
        for (int i = 0; i < 4; ++i) {
            af[i]  = *(const bf16x8*)&As[ra[i]];
            bfr[i] = *(const bf16x8*)&Bs[rb[i]];
        }
#pragma unroll
        for (int i = 0; i < 4; ++i)
#pragma unroll
            for (int j = 0; j < 4; ++j)
                acc[i][j] = __builtin_amdgcn_mfma_f32_16x16x32_bf16(af[i], bfr[j], acc[i][j], 0, 0, 0);
    }
#pragma unroll
    for (int i = 0; i < 4; ++i) {
        int rbase = m0 + wr * 64 + i * 16 + fc * 4;
#pragma unroll
        for (int j = 0; j < 4; ++j) {
            int col = n0 + wc * 64 + j * 16 + fr;
#pragma unroll
            for (int r2 = 0; r2 < 4; ++r2)
                out[(long)(rbase + r2) * 256 + col] = acc[i][j][r2];
        }
    }
}

// ---------------------------------------------------------------------------
// Generic bf16 MFMA GEMM: C[M,N] = act(A[M,K] @ B[N,K]^T + bias)
// ---------------------------------------------------------------------------
template <int RELU, int OUTBF>
__global__ __launch_bounds__(256) void bgemm_kernel(
    const unsigned short* __restrict__ A,    // [M][K] bf16
    const unsigned short* __restrict__ B,    // [N][K] bf16
    const float* __restrict__ bias,
    float* __restrict__ Cf, unsigned short* __restrict__ Cb,
    int M, int N, int K) {
    __shared__ __align__(16) short As[4096];
    __shared__ __align__(16) short Bs[4096];
    const int t = threadIdx.x;
    const int m0 = blockIdx.x * 128;
    const int n0 = blockIdx.y * 128;
    const int rA0 = t >> 2, rA1 = 64 + (t >> 2), cs = t & 3;
    short* aw0 = &As[rA0 * 32 + ((cs ^ ((rA0 >> 1) & 3)) * 8)];
    short* aw1 = &As[rA1 * 32 + ((cs ^ ((rA1 >> 1) & 3)) * 8)];
    short* bw0 = &Bs[rA0 * 32 + ((cs ^ ((rA0 >> 1) & 3)) * 8)];
    short* bw1 = &Bs[rA1 * 32 + ((cs ^ ((rA1 >> 1) & 3)) * 8)];
    const unsigned short* a0p = A + (long)(m0 + rA0) * K + cs * 8;
    const unsigned short* a1p = A + (long)(m0 + rA1) * K + cs * 8;
    const unsigned short* b0p = B + (long)(n0 + rA0) * K + cs * 8;
    const unsigned short* b1p = B + (long)(n0 + rA1) * K + cs * 8;

    const int lane = t & 63, wid = t >> 6;
    const int wr = wid >> 1, wc = wid & 1;
    const int fr = lane & 15, fc = lane >> 4;
    int ra[4], rb[4];
#pragma unroll
    for (int i = 0; i < 4; ++i) {
        int r = wr * 64 + i * 16 + fr;
        ra[i] = r * 32 + ((fc ^ ((r >> 1) & 3)) * 8);
        int rn = wc * 64 + i * 16 + fr;
        rb[i] = rn * 32 + ((fc ^ ((rn >> 1) & 3)) * 8);
    }
    f32x4 acc[4][4];
#pragma unroll
    for (int i = 0; i < 4; ++i)
#pragma unroll
        for (int j = 0; j < 4; ++j) acc[i][j] = (f32x4){0.f, 0.f, 0.f, 0.f};

    uint4 av0 = *(const uint4*)(a0p);
    uint4 av1 = *(const uint4*)(a1p);
    uint4 bv0 = *(const uint4*)(b0p);
    uint4 bv1 = *(const uint4*)(b1p);
    const int steps = K >> 5;
    for (int step = 0; step < steps; ++step) {
        __syncthreads();
        *(uint4*)aw0 = av0; *(uint4*)aw1 = av1;
        *(uint4*)bw0 = bv0; *(uint4*)bw1 = bv1;
        __syncthreads();
        if (step < steps - 1) {
            int k0 = (step + 1) * 32;
            av0 = *(const uint4*)(a0p + k0);
            av1 = *(const uint4*)(a1p + k0);
            bv0 = *(const uint4*)(b0p + k0);
            bv1 = *(const uint4*)(b1p + k0);
        }
        bf16x8 af[4], bfr[4];
#pragma unroll
        for (int i = 0; i < 4; ++i) {
            af[i]  = *(const bf16x8*)&As[ra[i]];
            bfr[i] = *(const bf16x8*)&Bs[rb[i]];
        }
#pragma unroll
        for (int i = 0; i < 4; ++i)
#pragma unroll
            for (int j = 0; j < 4; ++j)
                acc[i][j] = __builtin_amdgcn_mfma_f32_16x16x32_bf16(af[i], bfr[j], acc[i][j], 0, 0, 0);
    }
#pragma unroll
    for (int i = 0; i < 4; ++i) {
        int rbase = m0 + wr * 64 + i * 16 + fc * 4;
#pragma unroll
        for (int j = 0; j < 4; ++j) {
            int col = n0 + wc * 64 + j * 16 + fr;
            float bv = bias ? bias[col] : 0.f;
#pragma unroll
            for (int r2 = 0; r2 < 4; ++r2) {
                float v = acc[i][j][r2] + bv;
                if (RELU) v = fmaxf(v, 0.f);
                if (OUTBF) Cb[(long)(rbase + r2) * N + col] = f2bf(v);
                else       Cf[(long)(rbase + r2) * N + col] = v;
            }
        }
    }
}

// ---------------------------------------------------------------------------
// BN stats over NHWC [50176][256], 32 groups of 8 channels. 784 blocks.
// ---------------------------------------------------------------------------
__global__ __launch_bounds__(256) void bn_stats2_nhwc(const float* __restrict__ x,
    double* __restrict__ stats) {
    int t = threadIdx.x;
    long base = (long)blockIdx.x * 64 * 256;
    double s = 0.0, ss = 0.0;
    for (int p = 0; p < 64; ++p) {
        float v = x[base + p * 256 + t];
        s += v; ss += (double)v * v;
    }
    __shared__ double sh[512];
    sh[t] = s; sh[256 + t] = ss;
    __syncthreads();
    if (t < 32) {
        double gs = 0.0, gss = 0.0;
#pragma unroll
        for (int j = 0; j < 8; ++j) { gs += sh[8 * t + j]; gss += sh[256 + 8 * t + j]; }
        atomicAdd(&stats[t * 2], gs);
        atomicAdd(&stats[t * 2 + 1], gss);
    }
}

// ---------------------------------------------------------------------------
// Stage-2 fused BN+ReLU+Gaussian pool on NHWC. One output pixel per block.
// ---------------------------------------------------------------------------
__global__ __launch_bounds__(256) void gauss_pool2_nhwc(const float* __restrict__ in,
    float* __restrict__ out, const double* __restrict__ stats,
    const float* __restrict__ gamma, const float* __restrict__ beta, GaussW gw) {
    int t = threadIdx.x;
    int g = t >> 3;
    double mean = stats[g * 2] * (1.0 / 401408.0);
    double var  = stats[g * 2 + 1] * (1.0 / 401408.0) - mean * mean;
    float rs = rsqrtf((float)var + 1e-5f);
    float sc = gamma[g] * rs;
    float shf = beta[g] - (float)mean * sc;
    int op = blockIdx.x;                 // b*3136 + oy*56 + ox
    int b = op / 3136, r = op % 3136;
    int oy = r / 56, ox = r % 56;
    float acc = 0.f;
#pragma unroll
    for (int dy = 0; dy < 5; ++dy) {
        int yy = 2 * oy + dy - 2;
        if ((unsigned)yy >= 112u) continue;
#pragma unroll
        for (int dx = 0; dx < 5; ++dx) {
            int xx = 2 * ox + dx - 2;
            if ((unsigned)xx >= 112u) continue;
            float v = in[(((long)b * 12544) + yy * 112 + xx) * 256 + t];
            v = fmaxf(v * sc + shf, 0.f);
            acc += v * gw.w[dy * 5 + dx];
        }
    }
    out[(long)op * 256 + t] = acc;
}

// ---------------------------------------------------------------------------
// BN stats over NHWC [12544][64]. 49 blocks.
// ---------------------------------------------------------------------------
__global__ __launch_bounds__(256) void bn_stats3_nhwc(const float* __restrict__ x,
    double* __restrict__ stats) {
    int t = threadIdx.x, c = t & 63, pr = t >> 6;
    long base = (long)blockIdx.x * 256 * 64;
    double s = 0.0, ss = 0.0;
    for (int p = pr; p < 256; p += 4) {
        float v = x[base + p * 64 + c];
        s += v; ss += (double)v * v;
    }
    __shared__ double sh[512];
    sh[t] = s; sh[256 + t] = ss;
    __syncthreads();
    if (t < 64) {
        double gs  = sh[t] + sh[64 + t] + sh[128 + t] + sh[192 + t];
        double gss = sh[256 + t] + sh[320 + t] + sh[384 + t] + sh[448 + t];
        atomicAdd(&stats[t * 2], gs);
        atomicAdd(&stats[t * 2 + 1], gss);
    }
}

// ---------------------------------------------------------------------------
// BN+ReLU elementwise on NHWC [12544][64]. 3136 blocks.
// ---------------------------------------------------------------------------
__global__ __launch_bounds__(256) void bnrelu3_nhwc(const float* __restrict__ in,
    float* __restrict__ out, const double* __restrict__ stats,
    const float* __restrict__ gamma, const float* __restrict__ beta) {
    int i = blockIdx.x * 256 + threadIdx.x;
    int c = i & 63;
    double mean = stats[c * 2] * (1.0 / 12544.0);
    double var  = stats[c * 2 + 1] * (1.0 / 12544.0) - mean * mean;
    float rs = rsqrtf((float)var + 1e-5f);
    float sc = gamma[c] * rs;
    float sh = beta[c] - (float)mean * sc;
    out[i] = fmaxf(in[i] * sc + sh, 0.f);
}

// ---------------------------------------------------------------------------
// permute w_mlp1 to bf16: wp[o, p*64+c] = bf(w[o, c*49+p])
// ---------------------------------------------------------------------------
__global__ __launch_bounds__(256) void wperm_kernel(const float* __restrict__ w,
    unsigned short* __restrict__ wp) {
    int gi = blockIdx.x * 256 + threadIdx.x;
    int o = gi / 3136, k = gi % 3136;
    int c = k & 63, p = k >> 6;
    wp[gi] = f2bf(w[(long)o * 3136 + c * 49 + p]);
}

// ---------------------------------------------------------------------------
// ROI align on NHWC feature (4,56,56,64) -> bf16 rows of A
// ---------------------------------------------------------------------------
__global__ __launch_bounds__(256) void roi_kernel(const float* __restrict__ fp,
    const float* __restrict__ boxes, const int* __restrict__ bidx,
    unsigned short* __restrict__ roi) {
    int gi = blockIdx.x * 256 + threadIdx.x;
    int c = gi & 63;
    int rest = gi >> 6;
    int p = rest % 49;
    int nb = rest / 49;
    int oy = p / 7, ox = p % 7;
    int b = bidx[nb];
    float x1 = boxes[nb * 4 + 0] * 0.25f - 0.5f;
    float y1 = boxes[nb * 4 + 1] * 0.25f - 0.5f;
    float x2 = boxes[nb * 4 + 2] * 0.25f - 0.5f;
    float y2 = boxes[nb * 4 + 3] * 0.25f - 0.5f;
    float bw = (x2 - x1) / 7.0f;
    float bh = (y2 - y1) / 7.0f;
    const float* fb = fp + (long)b * 3136 * 64;
    float acc = 0.f;
#pragma unroll
    for (int iy = 0; iy < 2; ++iy) {
        float gy = ((float)(oy * 2 + iy) + 0.5f) / 2.0f;
        float ys = y1 + bh * gy;
        bool vy = (ys >= -1.0f) && (ys <= 56.0f);
        float yc = fminf(fmaxf(ys, 0.f), 55.f);
        float y0f = floorf(yc);
        int y0 = (int)y0f;
        int yp = min(y0 + 1, 55);
        float ly = yc - y0f, hy = 1.f - ly;
#pragma unroll
        for (int ix = 0; ix < 2; ++ix) {
            float gx = ((float)(ox * 2 + ix) + 0.5f) / 2.0f;
            float xs = x1 + bw * gx;
            bool vx = (xs >= -1.0f) && (xs <= 56.0f);
            float xc = fminf(fmaxf(xs, 0.f), 55.f);
            float x0f = floorf(xc);
            int x0 = (int)x0f;
            int xp = min(x0 + 1, 55);
            float lx = xc - x0f, hx = 1.f - lx;
            float v00 = fb[(y0 * 56 + x0) * 64 + c];
            float v01 = fb[(y0 * 56 + xp) * 64 + c];
            float v10 = fb[(yp * 56 + x0) * 64 + c];
            float v11 = fb[(yp * 56 + xp) * 64 + c];
            float v = v00 * (hy * hx) + v01 * (hy * lx) + v10 * (ly * hx) + v11 * (ly * lx);
            acc += (vy && vx) ? v : 0.f;
        }
    }
    roi[(long)rest * 64 + c] = f2bf(acc * 0.25f);
}

// ---------------------------------------------------------------------------
// fp32 SIMT GEMM (small N: conv3, heads). C = act(A @ W^T + bias)
// ---------------------------------------------------------------------------
__global__ __launch_bounds__(256) void gemm_kernel(const float* __restrict__ A,
    const float* __restrict__ W, const float* __restrict__ bias,
    float* __restrict__ C, int M, int N, int K, int ldw, int relu) {
    __shared__ float As[16][68];
    __shared__ float Ws[16][68];
    const int t = threadIdx.x;
    const int m0 = blockIdx.y * 64, n0 = blockIdx.x * 64;
    const int tx = t & 15, ty = t >> 4;
    const int lm = t >> 2, lk = (t & 3) * 4;
    float acc[4][4] = {};
    for (int k0 = 0; k0 < K; k0 += 16) {
        float4 av = *(const float4*)(A + (long)(m0 + lm) * K + (k0 + lk));
        float4 wv = make_float4(0.f, 0.f, 0.f, 0.f);
        if (n0 + lm < N) wv = *(const float4*)(W + (long)(n0 + lm) * ldw + (k0 + lk));
        As[lk + 0][lm] = av.x; As[lk + 1][lm] = av.y; As[lk + 2][lm] = av.z; As[lk + 3][lm] = av.w;
        Ws[lk + 0][lm] = wv.x; Ws[lk + 1][lm] = wv.y; Ws[lk + 2][lm] = wv.z; Ws[lk + 3][lm] = wv.w;
        __syncthreads();
#pragma unroll
        for (int k = 0; k < 16; ++k) {
            float4 a = *(const float4*)&As[k][ty * 4];
            float4 bv = *(const float4*)&Ws[k][tx * 4];
            acc[0][0] += a.x * bv.x; acc[0][1] += a.x * bv.y; acc[0][2] += a.x * bv.z; acc[0][3] += a.x * bv.w;
            acc[1][0] += a.y * bv.x; acc[1][1] += a.y * bv.y; acc[1][2] += a.y * bv.z; acc[1][3] += a.y * bv.w;
            acc[2][0] += a.z * bv.x; acc[2][1] += a.z * bv.y; acc[2][2] += a.z * bv.z; acc[2][3] += a.z * bv.w;
            acc[3][0] += a.w * bv.x; acc[3][1] += a.w * bv.y; acc[3][2] += a.w * bv.z; acc[3][3] += a.w * bv.w;
        }
        __syncthreads();
    }
#pragma unroll
    for (int i = 0; i < 4; ++i) {
        int m = m0 + ty * 4 + i;
#pragma unroll
        for (int j = 0; j < 4; ++j) {
            int n = n0 + tx * 4 + j;
            if (n < N) {
                float v = acc[i][j] + (bias ? bias[n] : 0.f);
                if (relu) v = fmaxf(v, 0.f);
                C[(long)m * N + n] = v;
            }
        }
    }
}

// ---------------------------------------------------------------------------
// attention dots
// ---------------------------------------------------------------------------
__global__ __launch_bounds__(256) void attn_dots_kernel(const float* __restrict__ h,
    const float* __restrict__ a_s, const float* __restrict__ a_d,
    float* __restrict__ es, float* __restrict__ ed, int heads) {
    int wid = (blockIdx.x * 256 + threadIdx.x) >> 6;
    int lane = threadIdx.x & 63;
    int hd = wid % heads;
    float4 hv = *(const float4*)&h[(long)wid * 256 + lane * 4];
    float4 av = *(const float4*)&a_s[hd * 256 + lane * 4];
    float4 dv = *(const float4*)&a_d[hd * 256 + lane * 4];
    float ps = hv.x * av.x + hv.y * av.y + hv.z * av.z + hv.w * av.w;
    float pd = hv.x * dv.x + hv.y * dv.y + hv.z * dv.z + hv.w * dv.w;
    for (int o = 32; o > 0; o >>= 1) {
        ps += __shfl_down(ps, o, 64);
        pd += __shfl_down(pd, o, 64);
    }
    if (lane == 0) { es[wid] = ps; ed[wid] = pd; }
}

// ---------------------------------------------------------------------------
// CSR build over dst
// ---------------------------------------------------------------------------
__global__ __launch_bounds__(256) void edge_count_kernel(const int* __restrict__ ei,
    int* __restrict__ cnt, int E, int tot) {
    int k = blockIdx.x * 256 + threadIdx.x;
    if (k >= tot) return;
    int d = (k < E) ? ei[E + k] : (k - E);
    atomicAdd(&cnt[d], 1);
}

__global__ __launch_bounds__(1024) void scan_kernel(const int* __restrict__ cnt,
    int* __restrict__ off) {
    __shared__ int sh[1024];
    int t = threadIdx.x;
    int base = t * 4;
    int c0 = cnt[base], c1 = cnt[base + 1], c2 = cnt[base + 2], c3 = cnt[base + 3];
    sh[t] = c0 + c1 + c2 + c3;
    __syncthreads();
    for (int d = 1; d < 1024; d <<= 1) {
        int v = (t >= d) ? sh[t - d] : 0;
        __syncthreads();
        sh[t] += v;
        __syncthreads();
    }
    int excl = (t == 0) ? 0 : sh[t - 1];
    off[base] = excl;
    off[base + 1] = excl + c0;
    off[base + 2] = excl + c0 + c1;
    off[base + 3] = excl + c0 + c1 + c2;
    if (t == 1023) off[4096] = sh[1023];
}

__global__ __launch_bounds__(256) void edge_scatter_kernel(const int* __restrict__ ei,
    const int* __restrict__ off, int* __restrict__ pos, int* __restrict__ eid,
    int E, int tot) {
    int k = blockIdx.x * 256 + threadIdx.x;
    if (k >= tot) return;
    int d = (k < E) ? ei[E + k] : (k - E);
    int p = atomicAdd(&pos[d], 1);
    eid[off[d] + p] = k;
}

// ---------------------------------------------------------------------------
// GAT aggregation. OUTBF: write bf16 (feeds next bgemm) else f32.
// ---------------------------------------------------------------------------
template <int HEADS, int OUTBF>
__global__ __launch_bounds__(256) void gat_aggregate_kernel(const float* __restrict__ h,
    const float* __restrict__ es, const float* __restrict__ ed,
    const int* __restrict__ off, const int* __restrict__ eid,
    const int* __restrict__ ei, const float* __restrict__ bias,
    void* __restrict__ outp, int E) {
    int n = blockIdx.x;
    int t = threadIdx.x;
    int o0 = off[n];
    int deg = off[n + 1] - o0;
    if (deg > 1024) deg = 1024;
    __shared__ float ew[4096];
    __shared__ int   srcs[1024];
    __shared__ float mden[2 * HEADS];
    for (int i = t; i < deg; i += 256) {
        int k = eid[o0 + i];
        int s = (k < E) ? ei[k] : (k - E);
        srcs[i] = s;
#pragma unroll
        for (int hd = 0; hd < HEADS; ++hd) {
            float e = es[s * HEADS + hd] + ed[n * HEADS + hd];
            e = (e >= 0.f) ? e : 0.2f * e;
            ew[i * HEADS + hd] = e;
        }
    }
    __syncthreads();
    if (t < HEADS) {
        float m = -1e30f;
        for (int i = 0; i < deg; ++i) m = fmaxf(m, ew[i * HEADS + t]);
        float den = 0.f;
        for (int i = 0; i < deg; ++i) den += expf(ew[i * HEADS + t] - m);
        mden[t] = m;
        mden[HEADS + t] = den + 1e-16f;
    }
    __syncthreads();
    for (int idx = t; idx < deg * HEADS; idx += 256) {
        int hd = idx % HEADS;
        ew[idx] = expf(ew[idx] - mden[hd]) / mden[HEADS + hd];
    }
    __syncthreads();
    float acc[HEADS];
#pragma unroll
    for (int hd = 0; hd < HEADS; ++hd) acc[hd] = 0.f;
    for (int i = 0; i < deg; ++i) {
        int s = srcs[i];
        const float* hr = &h[(long)s * HEADS * 256];
#pragma unroll
        for (int hd = 0; hd < HEADS; ++hd)
            acc[hd] += ew[i * HEADS + hd] * hr[hd * 256 + t];
    }
#pragma unroll
    for (int hd = 0; hd < HEADS; ++hd) {
        float v = acc[hd] + bias[hd * 256 + t];
        long oi = ((long)n * HEADS + hd) * 256 + t;
        if (OUTBF) ((unsigned short*)outp)[oi] = f2bf(v);
        else       ((float*)outp)[oi] = v;
    }
}

// ---------------------------------------------------------------------------
// rel_logits[e,o] = P1[src_e,o] + P2[dst_e,o] + b_rel[o]
// ---------------------------------------------------------------------------
__global__ __launch_bounds__(256) void rel_scatter_kernel(const float* __restrict__ P1,
    const float* __restrict__ P2, const float* __restrict__ brel,
    const int* __restrict__ ei, float* __restrict__ out, int E) {
    int gi = blockIdx.x * 256 + threadIdx.x;
    int o = gi & 63;
    int e = gi >> 6;
    if (o >= 51 || e >= E) return;
    int s = ei[e], d = ei[E + e];
    out[(long)e * 51 + o] = P1[(long)s * 51 + o] + P2[(long)d * 51 + o] + brel[o];
}

// ---------------------------------------------------------------------------
extern "C" void kernel_launch(void* const* d_in, const int* in_sizes, int n_in,
                              void* d_out, int out_size, void* d_ws, size_t ws_size,
                              hipStream_t stream) {
    const float* images = (const float*)d_in[0];
    const float* boxes  = (const float*)d_in[1];
    const int*   bidx   = (const int*)d_in[2];
    const int*   ei     = (const int*)d_in[3];
    const float* w1     = (const float*)d_in[4];
    const float* g1     = (const float*)d_in[5];
    const float* b1     = (const float*)d_in[6];
    const float* w2     = (const float*)d_in[7];
    const float* g2     = (const float*)d_in[8];
    const float* b2     = (const float*)d_in[9];
    const float* w3     = (const float*)d_in[10];
    const float* g3     = (const float*)d_in[11];
    const float* b3     = (const float*)d_in[12];
    const float* wm1    = (const float*)d_in[13];
    const float* bm1    = (const float*)d_in[14];
    const float* wm2    = (const float*)d_in[15];
    const float* bm2    = (const float*)d_in[16];
    const float* wg1    = (const float*)d_in[17];
    const float* as1    = (const float*)d_in[18];
    const float* ad1    = (const float*)d_in[19];
    const float* bias1  = (const float*)d_in[20];
    const float* wg2    = (const float*)d_in[21];
    const float* as2    = (const float*)d_in[22];
    const float* ad2    = (const float*)d_in[23];
    const float* bias2  = (const float*)d_in[24];
    const float* wobj   = (const float*)d_in[25];
    const float* bobj   = (const float*)d_in[26];
    const float* wrel   = (const float*)d_in[27];
    const float* brel   = (const float*)d_in[28];

    float* ws = (float*)d_ws;
    float* out = (float*)d_out;
    const int E = 65536, TOT = 69632;

    float*  Y1   = ws + Y1_F;
    float*  Y2   = ws + Y2_F;
    float*  Y3N  = ws + Y3N_F;
    float*  Y4N  = ws + Y4N_F;
    float*  Y5N  = ws + Y5N_F;
    float*  Y5T  = ws + Y5T_F;
    float*  HG1  = ws + HG1_F;
    float*  ES1  = ws + ES1_F;
    float*  ED1  = ws + ED1_F;
    float*  HG2  = ws + HG2_F;
    float*  ES2  = ws + ES2_F;
    float*  ED2  = ws + ED2_F;
    float*  O2   = ws + O2_F;
    float*  P1   = ws + P1_F;
    float*  P2   = ws + P2_F;
    unsigned short* Y2BF = (unsigned short*)(ws + Y2BF_F);
    unsigned short* WT2  = (unsigned short*)(ws + WT2_F);
    unsigned short* ROIb = (unsigned short*)(ws + ROI_F);
    unsigned short* WPb  = (unsigned short*)(ws + WP_F);
    unsigned short* H1b  = (unsigned short*)(ws + H1_F);
    unsigned short* H2b  = (unsigned short*)(ws + H2_F);
    unsigned short* O1b  = (unsigned short*)(ws + O1_F);
    unsigned short* WM2b = (unsigned short*)(ws + WM2B_F);
    unsigned short* WG1b = (unsigned short*)(ws + WG1B_F);
    unsigned short* WG2b = (unsigned short*)(ws + WG2B_F);
    double* SD  = (double*)(ws + STATS_F);
    int*    CNT = (int*)(ws + CNT_F);
    int*    POS = (int*)(ws + POS_F);
    int*    OFF = (int*)(ws + OFF_F);
    int*    EID = (int*)(ws + EID_F);

    GaussW gw;
    K5 k5;
    {
        float k1[5];
        float s2 = 2.0f * 0.66f * 0.66f;
        for (int i = 0; i < 5; ++i) {
            float r = (float)i - 2.0f;
            k1[i] = expf(-r * r / s2);
        }
        float tot = 0.f;
        for (int i = 0; i < 5; ++i)
            for (int j = 0; j < 5; ++j) { gw.w[i * 5 + j] = k1[i] * k1[j]; tot += gw.w[i * 5 + j]; }
        for (int i = 0; i < 25; ++i) gw.w[i] /= tot;
        float s1 = 0.f;
        for (int i = 0; i < 5; ++i) s1 += k1[i];
        for (int i = 0; i < 5; ++i) k5.k[i] = k1[i] / s1;   // outer(k5,k5) == gw
    }

    // zero stats (512 f) + CNT (4096 i) + POS (4096 i), contiguous
    hipMemsetAsync((char*)d_ws + STATS_F * 4, 0, (512 + 4096 + 4096) * 4, stream);

    // stage 1 (NCHW fp32): plain conv1 + separate stats + staged separable pool
    conv1_kernel<<<12544, 256, 0, stream>>>(images, w1, Y1);
    bn_stats_kernel<<<dim3(128, 16), 256, 0, stream>>>(Y1, SD, 128, 50176, 8, 4);
    gauss_pool1_sep<<<4 * 128 * 14, 256, 0, stream>>>(Y1, Y2, SD, g1, b1, k5);
    // stage 2 (MFMA implicit GEMM, NHWC)
    nchw2nhwc_bf16<<<784, 256, 0, stream>>>(Y2, Y2BF);
    wt2_kernel<<<1152, 256, 0, stream>>>(w2, WT2);
    conv2_mfma<<<dim3(392, 2), 256, 0, stream>>>(Y2BF, WT2, Y3N);
    bn_stats2_nhwc<<<784, 256, 0, stream>>>(Y3N, SD + 32);
    gauss_pool2_nhwc<<<12544, 256, 0, stream>>>(Y3N, Y4N, SD + 32, g2, b2, gw);
    // stage 3 (1x1 conv == fp32 GEMM on NHWC)
    gemm_kernel<<<dim3(1, 196), 256, 0, stream>>>(Y4N, w3, nullptr, Y5N, 12544, 64, 256, 256, 0);
    bn_stats3_nhwc<<<49, 256, 0, stream>>>(Y5N, SD + 96);
    bnrelu3_nhwc<<<3136, 256, 0, stream>>>(Y5N, Y5T, SD + 96, g3, b3);
    // bf16 weight prep (in dead Y3N region -> must be after gauss_pool2)
    // w_gat1 (1024x256) and w_gat2 (256x1024) are 262,144 elements each.
    wperm_kernel<<<3136, 256, 0, stream>>>(wm1, WPb);
    castbf_kernel<<<256, 256, 0, stream>>>(wm2, WM2b, 65536);
    castbf_kernel<<<1024, 256, 0, stream>>>(wg1, WG1b, 262144);
    castbf_kernel<<<1024, 256, 0, stream>>>(wg2, WG2b, 262144);
    // ROI align + MLP (bf16 MFMA)
    roi_kernel<<<50176, 256, 0, stream>>>(Y5T, boxes, bidx, ROIb);
    bgemm_kernel<1, 1><<<dim3(32, 2), 256, 0, stream>>>(ROIb, WPb, bm1, nullptr, H1b, 4096, 256, 3136);
    bgemm_kernel<1, 1><<<dim3(32, 2), 256, 0, stream>>>(H1b, WM2b, bm2, nullptr, H2b, 4096, 256, 256);
    // CSR over dst (shared by both GAT layers)
    edge_count_kernel<<<272, 256, 0, stream>>>(ei, CNT, E, TOT);
    scan_kernel<<<1, 1024, 0, stream>>>(CNT, OFF);
    edge_scatter_kernel<<<272, 256, 0, stream>>>(ei, OFF, POS, EID, E, TOT);
    // GAT layer 1 (4 heads, concat)
    bgemm_kernel<0, 0><<<dim3(32, 8), 256, 0, stream>>>(H2b, WG1b, nullptr, HG1, nullptr, 4096, 1024, 256);
    attn_dots_kernel<<<4096, 256, 0, stream>>>(HG1, as1, ad1, ES1, ED1, 4);
    gat_aggregate_kernel<4, 1><<<4096, 256, 0, stream>>>(HG1, ES1, ED1, OFF, EID, ei, bias1, O1b, E);
    // GAT layer 2 (1 head)
    bgemm_kernel<0, 0><<<dim3(32, 2), 256, 0, stream>>>(O1b, WG2b, nullptr, HG2, nullptr, 4096, 256, 1024);
    attn_dots_kernel<<<1024, 256, 0, stream>>>(HG2, as2, ad2, ES2, ED2, 1);
    gat_aggregate_kernel<1, 0><<<4096, 256, 0, stream>>>(HG2, ES2, ED2, OFF, EID, ei, bias2, O2, E);
    // heads (fp32, small N)
    gemm_kernel<<<dim3(3, 64), 256, 0, stream>>>(O2, wobj, bobj, out, 4096, 151, 256, 256, 0);
    gemm_kernel<<<dim3(1, 64), 256, 0, stream>>>(O2, wrel, nullptr, P1, 4096, 51, 256, 512, 0);
    gemm_kernel<<<dim3(1, 64), 256, 0, stream>>>(O2, wrel + 256, nullptr, P2, 4096, 51, 256, 512, 0);
    rel_scatter_kernel<<<16384, 256, 0, stream>>>(P1, P2, brel, ei, out + 618496, E);
}

// Round 13
// 707.206 us; speedup vs baseline: 1.1668x; 1.0513x over previous
//
#include <hip/hip_runtime.h>
#include <hip/hip_bf16.h>
#include <cmath>

// ---------------------------------------------------------------------------
// Workspace layout (float offsets). ~153 MB footprint (unchanged).
// ---------------------------------------------------------------------------
constexpr long Y1_F    = 0;          // 4x128x224x224 = 25,690,112
constexpr long Y3N_F   = 0;          // 50176x256     = 12,845,056 (NHWC f32)
constexpr long WM2B_F  = 0;          // 256x256 bf16   (after Y3N dead)
constexpr long WG1B_F  = 65536;      // 1024x256 bf16  = 131,072 floats
constexpr long WG2B_F  = 589824;     // 256x1024 bf16  = 131,072 floats
constexpr long ROI_F   = 12845056;   // 4096x3136 bf16 = 6,422,528 floats
constexpr long Y2BF_F  = 12845056;   // 4x12544x128 bf16 (stage2 only)
constexpr long WT2_F   = 16056320;   // 256x1152 bf16
constexpr long O1_F    = 12845056;   // 4096x1024 bf16 (ROIbf dead by then)
constexpr long HG2_F   = 17039360;   // 4096x256 f32
constexpr long ES2_F   = 18087936;   // 4096
constexpr long ED2_F   = 18092032;   // 4096
constexpr long O2_F    = 18096128;   // 4096x256 f32
constexpr long Y2_F    = 25690112;   // 4x128x112x112 f32 (stage1 out)
constexpr long HG1_F   = 25690112;   // 4096x1024 f32 (Y2 dead)
constexpr long ES1_F   = 29884416;   // 4096x4
constexpr long ED1_F   = 29900800;   // 4096x4
constexpr long Y4N_F   = 32112640;   // 4x3136x256 f32
constexpr long H1_F    = 32112640;   // 4096x256 bf16 (Y4N dead)
constexpr long H2_F    = 33161216;   // 4096x256 bf16
constexpr long Y5N_F   = 35323904;   // 12544x64 f32
constexpr long STATS_F = 36126720;   // 256 doubles (512 floats)
constexpr long CNT_F   = 36127232;   // 4096 ints
constexpr long POS_F   = 36131328;   // 4096 ints
constexpr long OFF_F   = 36135424;   // 4097 ints (pad 4104)
constexpr long EID_F   = 36139528;   // 69632 ints
constexpr long Y5T_F   = 36209160;   // 12544x64 f32 post-BN/ReLU
constexpr long WP_F    = 37011976;   // 256x3136 bf16 permuted w_mlp1
constexpr long P1_F    = 37814792;   // 4096x51
constexpr long P2_F    = 38023688;   // 4096x51  -> end 38,232,584 floats

struct GaussW { float w[25]; };
struct K5     { float k[5]; };

typedef __attribute__((ext_vector_type(8))) short bf16x8;
typedef __attribute__((ext_vector_type(4))) float f32x4;

static __device__ __forceinline__ unsigned short f2bf(float f) {
    unsigned int u = __float_as_uint(f);
    unsigned int r = (u + 0x7fffu + ((u >> 16) & 1u)) >> 16;   // RNE
    return (unsigned short)r;
}

// ---------------------------------------------------------------------------
// conv1: 3->128, 3x3, pad1, 224x224 (NCHW fp32). Plain (R11 fusion reverted).
// ---------------------------------------------------------------------------
__global__ __launch_bounds__(256) void conv1_kernel(const float* __restrict__ img,
    const float* __restrict__ w, float* __restrict__ out) {
    int pb  = blockIdx.x % 196;
    int ocg = (blockIdx.x / 196) % 16;
    int b   = blockIdx.x / (196 * 16);
    int pix = pb * 256 + threadIdx.x;
    int y = pix / 224, x = pix % 224;
    const float* ib = img + (long)b * 3 * 50176;
    float in[27];
#pragma unroll
    for (int c = 0; c < 3; ++c)
#pragma unroll
        for (int dy = 0; dy < 3; ++dy) {
            int yy = y + dy - 1;
            bool oky = (unsigned)yy < 224u;
#pragma unroll
            for (int dx = 0; dx < 3; ++dx) {
                int xx = x + dx - 1;
                bool ok = oky && ((unsigned)xx < 224u);
                in[(c * 3 + dy) * 3 + dx] = ok ? ib[(c * 224 + yy) * 224 + xx] : 0.f;
            }
        }
    const float* wb = w + ocg * 8 * 27;
    float* ob = out + ((long)(b * 128 + ocg * 8)) * 50176 + pix;
#pragma unroll
    for (int o = 0; o < 8; ++o) {
        float a = 0.f;
#pragma unroll
        for (int j = 0; j < 27; ++j) a += in[j] * wb[o * 27 + j];
        ob[(long)o * 50176] = a;
    }
}

// ---------------------------------------------------------------------------
// BN stats (NCHW, stage 1): per-group sum/sumsq via double atomics
// ---------------------------------------------------------------------------
__global__ __launch_bounds__(256) void bn_stats_kernel(const float* __restrict__ x,
    double* __restrict__ stats, int C, int HW, int fs, int B) {
    int g = blockIdx.y;
    int fsHW = fs * HW;
    double s = 0.0, ss = 0.0;
    for (int b = 0; b < B; ++b) {
        const float* xb = x + ((long)b * C + (long)g * fs) * HW;
        for (int r = blockIdx.x * 256 + threadIdx.x; r < fsHW; r += gridDim.x * 256) {
            float v = xb[r];
            s += v; ss += (double)v * v;
        }
    }
    __shared__ double sh[512];
    sh[threadIdx.x] = s; sh[256 + threadIdx.x] = ss;
    __syncthreads();
    for (int st = 128; st > 0; st >>= 1) {
        if (threadIdx.x < st) {
            sh[threadIdx.x] += sh[threadIdx.x + st];
            sh[256 + threadIdx.x] += sh[256 + threadIdx.x + st];
        }
        __syncthreads();
    }
    if (threadIdx.x == 0) {
        atomicAdd(&stats[g * 2], sh[0]);
        atomicAdd(&stats[g * 2 + 1], sh[256]);
    }
}

// ---------------------------------------------------------------------------
// Stage-1 fused BN+ReLU + SEPARABLE Gaussian pool (NCHW), LDS-staged input.
// ---------------------------------------------------------------------------
__global__ __launch_bounds__(256) void gauss_pool1_sep(const float* __restrict__ in,
    float* __restrict__ out, const double* __restrict__ stats,
    const float* __restrict__ gamma, const float* __restrict__ beta, K5 kk) {
    __shared__ float ibuf[19 * 224];
    __shared__ float hbuf[19 * 112];
    int blk = blockIdx.x;
    int tile = blk % 14;
    int c = (blk / 14) % 128;
    int b = blk / (14 * 128);
    int t = threadIdx.x;
    int g = c >> 3;
    double mean = stats[g * 2] * (1.0 / 1605632.0);
    double var  = stats[g * 2 + 1] * (1.0 / 1605632.0) - mean * mean;
    float rs = rsqrtf((float)var + 1e-5f);
    float sc = gamma[g] * rs;
    float sh = beta[g] - (float)mean * sc;
    const float* ib = in + ((long)(b * 128 + c)) * 50176;
    int y0 = tile * 16 - 2;
    for (int i = t; i < 19 * 224; i += 256) {
        int yl = i / 224, x = i % 224;
        int yy = y0 + yl;
        float v = 0.f;
        if ((unsigned)yy < 224u)
            v = fmaxf(ib[yy * 224 + x] * sc + sh, 0.f);
        ibuf[i] = v;
    }
    __syncthreads();
    for (int i = t; i < 19 * 112; i += 256) {
        int yl = i / 112, ox = i % 112;
        const float* row = &ibuf[yl * 224];
        int xb = 2 * ox - 2;
        float acc = 0.f;
#pragma unroll
        for (int dx = 0; dx < 5; ++dx) {
            int xx = xb + dx;
            if ((unsigned)xx < 224u) acc += kk.k[dx] * row[xx];
        }
        hbuf[i] = acc;
    }
    __syncthreads();
    float* ob = out + ((long)(b * 128 + c)) * 12544 + (tile * 8) * 112;
    for (int i = t; i < 8 * 112; i += 256) {
        int oyl = i / 112, ox = i % 112;
        float acc = 0.f;
#pragma unroll
        for (int dy = 0; dy < 5; ++dy)
            acc += kk.k[dy] * hbuf[(2 * oyl + dy) * 112 + ox];
        ob[oyl * 112 + ox] = acc;
    }
}

// ---------------------------------------------------------------------------
// Y2 NCHW f32 -> NHWC bf16 (LDS tiled transpose)
// ---------------------------------------------------------------------------
__global__ __launch_bounds__(256) void nchw2nhwc_bf16(const float* __restrict__ in,
    unsigned short* __restrict__ out) {
    __shared__ float tile[128][65];
    int blk = blockIdx.x;
    int b = blk / 196, p0 = (blk % 196) * 64;
    int t = threadIdx.x;
#pragma unroll 4
    for (int i = 0; i < 32; ++i) {
        int idx = i * 256 + t; int c = idx >> 6; int p = idx & 63;
        tile[c][p] = in[((long)(b * 128 + c)) * 12544 + p0 + p];
    }
    __syncthreads();
#pragma unroll 4
    for (int i = 0; i < 32; ++i) {
        int idx = i * 256 + t; int p = idx >> 7; int c = idx & 127;
        out[((long)(b * 12544) + p0 + p) * 128 + c] = f2bf(tile[c][p]);
    }
}

// ---------------------------------------------------------------------------
// w2 [256][128][3][3] f32 -> Wt [256][k=(dy*3+dx)*128+c] bf16
// ---------------------------------------------------------------------------
__global__ __launch_bounds__(256) void wt2_kernel(const float* __restrict__ w,
    unsigned short* __restrict__ out) {
    int i = blockIdx.x * 256 + threadIdx.x;
    int o = i / 1152, k = i % 1152;
    int dydx = k >> 7, c = k & 127;
    out[i] = f2bf(w[(o * 128 + c) * 9 + dydx]);
}

// ---------------------------------------------------------------------------
// generic f32 -> bf16 cast
// ---------------------------------------------------------------------------
__global__ __launch_bounds__(256) void castbf_kernel(const float* __restrict__ src,
    unsigned short* __restrict__ dst, int n) {
    int i = blockIdx.x * 256 + threadIdx.x;
    if (i < n) dst[i] = f2bf(src[i]);
}

// ---------------------------------------------------------------------------
// conv2 as implicit MFMA GEMM: C[50176][256] = patches(X) @ Wt^T
// ---------------------------------------------------------------------------
__global__ __launch_bounds__(256) void conv2_mfma(
    const unsigned short* __restrict__ X,    // [4][12544][128] bf16
    const unsigned short* __restrict__ Wt,   // [256][1152] bf16
    float* __restrict__ out) {               // [50176][256] f32 (NHWC)
    __shared__ __align__(16) short As[4096];
    __shared__ __align__(16) short Bs[4096];
    const int t = threadIdx.x;
    const int m0 = blockIdx.x * 128;
    const int n0 = blockIdx.y * 128;
    const int b  = m0 / 12544;
    const int pb = m0 % 12544;

    const int rA0 = t >> 2, rA1 = 64 + (t >> 2), cs = t & 3;
    const int p0 = pb + rA0, p1 = pb + rA1;
    const int y0 = p0 / 112, x0 = p0 % 112;
    const int y1 = p1 / 112, x1 = p1 % 112;
    short* aw0 = &As[rA0 * 32 + ((cs ^ ((rA0 >> 1) & 3)) * 8)];
    short* aw1 = &As[rA1 * 32 + ((cs ^ ((rA1 >> 1) & 3)) * 8)];
    short* bw0 = &Bs[rA0 * 32 + ((cs ^ ((rA0 >> 1) & 3)) * 8)];
    short* bw1 = &Bs[rA1 * 32 + ((cs ^ ((rA1 >> 1) & 3)) * 8)];
    const unsigned short* a0p = X + ((long)b * 12544 + p0) * 128 + cs * 8;
    const unsigned short* a1p = X + ((long)b * 12544 + p1) * 128 + cs * 8;
    const unsigned short* b0p = Wt + (long)(n0 + rA0) * 1152 + cs * 8;
    const unsigned short* b1p = Wt + (long)(n0 + rA1) * 1152 + cs * 8;

    const int lane = t & 63, wid = t >> 6;
    const int wr = wid >> 1, wc = wid & 1;
    const int fr = lane & 15, fc = lane >> 4;
    int ra[4], rb[4];
#pragma unroll
    for (int i = 0; i < 4; ++i) {
        int r = wr * 64 + i * 16 + fr;
        ra[i] = r * 32 + ((fc ^ ((r >> 1) & 3)) * 8);
        int rn = wc * 64 + i * 16 + fr;
        rb[i] = rn * 32 + ((fc ^ ((rn >> 1) & 3)) * 8);
    }
    f32x4 acc[4][4];
#pragma unroll
    for (int i = 0; i < 4; ++i)
#pragma unroll
        for (int j = 0; j < 4; ++j) acc[i][j] = (f32x4){0.f, 0.f, 0.f, 0.f};

    uint4 av0, av1, bv0, bv1;
    {
        int yy0 = y0 - 1, xx0 = x0 - 1, yy1 = y1 - 1, xx1 = x1 - 1;
        const int off = (-112 - 1) * 128;
        av0 = ((unsigned)yy0 < 112u && (unsigned)xx0 < 112u) ? *(const uint4*)(a0p + off) : make_uint4(0, 0, 0, 0);
        av1 = ((unsigned)yy1 < 112u && (unsigned)xx1 < 112u) ? *(const uint4*)(a1p + off) : make_uint4(0, 0, 0, 0);
        bv0 = *(const uint4*)(b0p);
        bv1 = *(const uint4*)(b1p);
    }
    for (int step = 0; step < 36; ++step) {
        __syncthreads();
        *(uint4*)aw0 = av0; *(uint4*)aw1 = av1;
        *(uint4*)bw0 = bv0; *(uint4*)bw1 = bv1;
        __syncthreads();
        if (step < 35) {
            int k0 = (step + 1) * 32;
            int dydx = k0 >> 7, coff = k0 & 127;
            int dy = dydx / 3 - 1, dx = dydx % 3 - 1;
            int off = (dy * 112 + dx) * 128 + coff;
            int yy0 = y0 + dy, xx0 = x0 + dx, yy1 = y1 + dy, xx1 = x1 + dx;
            av0 = ((unsigned)yy0 < 112u && (unsigned)xx0 < 112u) ? *(const uint4*)(a0p + off) : make_uint4(0, 0, 0, 0);
            av1 = ((unsigned)yy1 < 112u && (unsigned)xx1 < 112u) ? *(const uint4*)(a1p + off) : make_uint4(0, 0, 0, 0);
            bv0 = *(const uint4*)(b0p + k0);
            bv1 = *(const uint4*)(b1p + k0);
        }
        bf16x8 af[4], bfr[4];
#pragma unroll
        for (int i = 0; i < 4; ++i) {
            af[i]  = *(const bf16x8*)&As[ra[i]];
            bfr[i] = *(const bf16x8*)&Bs[rb[i]];
        }
#pragma unroll
        for (int i = 0; i < 4; ++i)
#pragma unroll
            for (int j = 0; j < 4; ++j)
                acc[i][j] = __builtin_amdgcn_mfma_f32_16x16x32_bf16(af[i], bfr[j], acc[i][j], 0, 0, 0);
    }
#pragma unroll
    for (int i = 0; i < 4; ++i) {
        int rbase = m0 + wr * 64 + i * 16 + fc * 4;
#pragma unroll
        for (int j = 0; j < 4; ++j) {
            int col = n0 + wc * 64 + j * 16 + fr;
#pragma unroll
            for (int r2 = 0; r2 < 4; ++r2)
                out[(long)(rbase + r2) * 256 + col] = acc[i][j][r2];
        }
    }
}

// ---------------------------------------------------------------------------
// Generic bf16 MFMA GEMM: C[M,N] = act(A[M,K] @ B[N,K]^T + bias)
// ---------------------------------------------------------------------------
template <int RELU, int OUTBF>
__global__ __launch_bounds__(256) void bgemm_kernel(
    const unsigned short* __restrict__ A,    // [M][K] bf16
    const unsigned short* __restrict__ B,    // [N][K] bf16
    const float* __restrict__ bias,
    float* __restrict__ Cf, unsigned short* __restrict__ Cb,
    int M, int N, int K) {
    __shared__ __align__(16) short As[4096];
    __shared__ __align__(16) short Bs[4096];
    const int t = threadIdx.x;
    const int m0 = blockIdx.x * 128;
    const int n0 = blockIdx.y * 128;
    const int rA0 = t >> 2, rA1 = 64 + (t >> 2), cs = t & 3;
    short* aw0 = &As[rA0 * 32 + ((cs ^ ((rA0 >> 1) & 3)) * 8)];
    short* aw1 = &As[rA1 * 32 + ((cs ^ ((rA1 >> 1) & 3)) * 8)];
    short* bw0 = &Bs[rA0 * 32 + ((cs ^ ((rA0 >> 1) & 3)) * 8)];
    short* bw1 = &Bs[rA1 * 32 + ((cs ^ ((rA1 >> 1) & 3)) * 8)];
    const unsigned short* a0p = A + (long)(m0 + rA0) * K + cs * 8;
    const unsigned short* a1p = A + (long)(m0 + rA1) * K + cs * 8;
    const unsigned short* b0p = B + (long)(n0 + rA0) * K + cs * 8;
    const unsigned short* b1p = B + (long)(n0 + rA1) * K + cs * 8;

    const int lane = t & 63, wid = t >> 6;
    const int wr = wid >> 1, wc = wid & 1;
    const int fr = lane & 15, fc = lane >> 4;
    int ra[4], rb[4];
#pragma unroll
    for (int i = 0; i < 4; ++i) {
        int r = wr * 64 + i * 16 + fr;
        ra[i] = r * 32 + ((fc ^ ((r >> 1) & 3)) * 8);
        int rn = wc * 64 + i * 16 + fr;
        rb[i] = rn * 32 + ((fc ^ ((rn >> 1) & 3)) * 8);
    }
    f32x4 acc[4][4];
#pragma unroll
    for (int i = 0; i < 4; ++i)
#pragma unroll
        for (int j = 0; j < 4; ++j) acc[i][j] = (f32x4){0.f, 0.f, 0.f, 0.f};

    uint4 av0 = *(const uint4*)(a0p);
    uint4 av1 = *(const uint4*)(a1p);
    uint4 bv0 = *(const uint4*)(b0p);
    uint4 bv1 = *(const uint4*)(b1p);
    const int steps = K >> 5;
    for (int step = 0; step < steps; ++step) {
        __syncthreads();
        *(uint4*)aw0 = av0; *(uint4*)aw1 = av1;
        *(uint4*)bw0 = bv0; *(uint4*)bw1 = bv1;
        __syncthreads();
        if (step < steps - 1) {
            int k0 = (step + 1) * 32;
            av0 = *(const uint4*)(a0p + k0);
            av1 = *(const uint4*)(a1p + k0);
            bv0 = *(const uint4*)(b0p + k0);
            bv1 = *(const uint4*)(b1p + k0);
        }
        bf16x8 af[4], bfr[4];
#pragma unroll
        for (int i = 0; i < 4; ++i) {
            af[i]  = *(const bf16x8*)&As[ra[i]];
            bfr[i] = *(const bf16x8*)&Bs[rb[i]];
        }
#pragma unroll
        for (int i = 0; i < 4; ++i)
#pragma unroll
            for (int j = 0; j < 4; ++j)
                acc[i][j] = __builtin_amdgcn_mfma_f32_16x16x32_bf16(af[i], bfr[j], acc[i][j], 0, 0, 0);
    }
#pragma unroll
    for (int i = 0; i < 4; ++i) {
        int rbase = m0 + wr * 64 + i * 16 + fc * 4;
#pragma unroll
        for (int j = 0; j < 4; ++j) {
            int col = n0 + wc * 64 + j * 16 + fr;
            float bv = bias ? bias[col] : 0.f;
#pragma unroll
            for (int r2 = 0; r2 < 4; ++r2) {
                float v = acc[i][j][r2] + bv;
                if (RELU) v = fmaxf(v, 0.f);
                if (OUTBF) Cb[(long)(rbase + r2) * N + col] = f2bf(v);
                else       Cf[(long)(rbase + r2) * N + col] = v;
            }
        }
    }
}

// ---------------------------------------------------------------------------
// BN stats over NHWC [50176][256], 32 groups of 8 channels. 784 blocks.
// ---------------------------------------------------------------------------
__global__ __launch_bounds__(256) void bn_stats2_nhwc(const float* __restrict__ x,
    double* __restrict__ stats) {
    int t = threadIdx.x;
    long base = (long)blockIdx.x * 64 * 256;
    double s = 0.0, ss = 0.0;
    for (int p = 0; p < 64; ++p) {
        float v = x[base + p * 256 + t];
        s += v; ss += (double)v * v;
    }
    __shared__ double sh[512];
    sh[t] = s; sh[256 + t] = ss;
    __syncthreads();
    if (t < 32) {
        double gs = 0.0, gss = 0.0;
#pragma unroll
        for (int j = 0; j < 8; ++j) { gs += sh[8 * t + j]; gss += sh[256 + 8 * t + j]; }
        atomicAdd(&stats[t * 2], gs);
        atomicAdd(&stats[t * 2 + 1], gss);
    }
}

// ---------------------------------------------------------------------------
// Stage-2 fused BN+ReLU+Gaussian pool on NHWC. One output pixel per block.
// ---------------------------------------------------------------------------
__global__ __launch_bounds__(256) void gauss_pool2_nhwc(const float* __restrict__ in,
    float* __restrict__ out, const double* __restrict__ stats,
    const float* __restrict__ gamma, const float* __restrict__ beta, GaussW gw) {
    int t = threadIdx.x;
    int g = t >> 3;
    double mean = stats[g * 2] * (1.0 / 401408.0);
    double var  = stats[g * 2 + 1] * (1.0 / 401408.0) - mean * mean;
    float rs = rsqrtf((float)var + 1e-5f);
    float sc = gamma[g] * rs;
    float shf = beta[g] - (float)mean * sc;
    int op = blockIdx.x;                 // b*3136 + oy*56 + ox
    int b = op / 3136, r = op % 3136;
    int oy = r / 56, ox = r % 56;
    float acc = 0.f;
#pragma unroll
    for (int dy = 0; dy < 5; ++dy) {
        int yy = 2 * oy + dy - 2;
        if ((unsigned)yy >= 112u) continue;
#pragma unroll
        for (int dx = 0; dx < 5; ++dx) {
            int xx = 2 * ox + dx - 2;
            if ((unsigned)xx >= 112u) continue;
            float v = in[(((long)b * 12544) + yy * 112 + xx) * 256 + t];
            v = fmaxf(v * sc + shf, 0.f);
            acc += v * gw.w[dy * 5 + dx];
        }
    }
    out[(long)op * 256 + t] = acc;
}

// ---------------------------------------------------------------------------
// BN stats over NHWC [12544][64]. 49 blocks.
// ---------------------------------------------------------------------------
__global__ __launch_bounds__(256) void bn_stats3_nhwc(const float* __restrict__ x,
    double* __restrict__ stats) {
    int t = threadIdx.x, c = t & 63, pr = t >> 6;
    long base = (long)blockIdx.x * 256 * 64;
    double s = 0.0, ss = 0.0;
    for (int p = pr; p < 256; p += 4) {
        float v = x[base + p * 64 + c];
        s += v; ss += (double)v * v;
    }
    __shared__ double sh[512];
    sh[t] = s; sh[256 + t] = ss;
    __syncthreads();
    if (t < 64) {
        double gs  = sh[t] + sh[64 + t] + sh[128 + t] + sh[192 + t];
        double gss = sh[256 + t] + sh[320 + t] + sh[384 + t] + sh[448 + t];
        atomicAdd(&stats[t * 2], gs);
        atomicAdd(&stats[t * 2 + 1], gss);
    }
}

// ---------------------------------------------------------------------------
// BN+ReLU elementwise on NHWC [12544][64]. 3136 blocks.
// ---------------------------------------------------------------------------
__global__ __launch_bounds__(256) void bnrelu3_nhwc(const float* __restrict__ in,
    float* __restrict__ out, const double* __restrict__ stats,
    const float* __restrict__ gamma, const float* __restrict__ beta) {
    int i = blockIdx.x * 256 + threadIdx.x;
    int c = i & 63;
    double mean = stats[c * 2] * (1.0 / 12544.0);
    double var  = stats[c * 2 + 1] * (1.0 / 12544.0) - mean * mean;
    float rs = rsqrtf((float)var + 1e-5f);
    float sc = gamma[c] * rs;
    float sh = beta[c] - (float)mean * sc;
    out[i] = fmaxf(in[i] * sc + sh, 0.f);
}

// ---------------------------------------------------------------------------
// permute w_mlp1 to bf16: wp[o, p*64+c] = bf(w[o, c*49+p])
// ---------------------------------------------------------------------------
__global__ __launch_bounds__(256) void wperm_kernel(const float* __restrict__ w,
    unsigned short* __restrict__ wp) {
    int gi = blockIdx.x * 256 + threadIdx.x;
    int o = gi / 3136, k = gi % 3136;
    int c = k & 63, p = k >> 6;
    wp[gi] = f2bf(w[(long)o * 3136 + c * 49 + p]);
}

// ---------------------------------------------------------------------------
// ROI align on NHWC feature (4,56,56,64) -> bf16 rows of A.
// R12 profile: per-channel version was VALU-bound (95% VALUBusy) — box math
// recomputed 64x per (nb,p). Now 4 channels/thread via float4 gathers:
// thread count /4, box math amortized 4x, dwordx4 loads, ushort4 store.
// grid = 4096*49*16/256 = 12544.
// ---------------------------------------------------------------------------
__global__ __launch_bounds__(256) void roi_kernel(const float* __restrict__ fp,
    const float* __restrict__ boxes, const int* __restrict__ bidx,
    unsigned short* __restrict__ roi) {
    int gi = blockIdx.x * 256 + threadIdx.x;
    int c4 = (gi & 15) * 4;          // channel base (4 channels per thread)
    int rest = gi >> 4;              // nb*49 + p
    int p = rest % 49;
    int nb = rest / 49;
    int oy = p / 7, ox = p % 7;
    int b = bidx[nb];
    float x1 = boxes[nb * 4 + 0] * 0.25f - 0.5f;
    float y1 = boxes[nb * 4 + 1] * 0.25f - 0.5f;
    float x2 = boxes[nb * 4 + 2] * 0.25f - 0.5f;
    float y2 = boxes[nb * 4 + 3] * 0.25f - 0.5f;
    float bw = (x2 - x1) / 7.0f;
    float bh = (y2 - y1) / 7.0f;
    const float* fb = fp + (long)b * 3136 * 64;
    float a0 = 0.f, a1 = 0.f, a2 = 0.f, a3 = 0.f;
#pragma unroll
    for (int iy = 0; iy < 2; ++iy) {
        float gy = ((float)(oy * 2 + iy) + 0.5f) / 2.0f;
        float ys = y1 + bh * gy;
        bool vy = (ys >= -1.0f) && (ys <= 56.0f);
        float yc = fminf(fmaxf(ys, 0.f), 55.f);
        float y0f = floorf(yc);
        int y0 = (int)y0f;
        int yp = min(y0 + 1, 55);
        float ly = yc - y0f, hy = 1.f - ly;
#pragma unroll
        for (int ix = 0; ix < 2; ++ix) {
            float gx = ((float)(ox * 2 + ix) + 0.5f) / 2.0f;
            float xs = x1 + bw * gx;
            bool vx = (xs >= -1.0f) && (xs <= 56.0f);
            float xc = fminf(fmaxf(xs, 0.f), 55.f);
            float x0f = floorf(xc);
            int x0 = (int)x0f;
            int xp = min(x0 + 1, 55);
            float lx = xc - x0f, hx = 1.f - lx;
            float w00 = hy * hx, w01 = hy * lx, w10 = ly * hx, w11 = ly * lx;
            bool ok = vy && vx;
            float4 v00 = *(const float4*)&fb[(y0 * 56 + x0) * 64 + c4];
            float4 v01 = *(const float4*)&fb[(y0 * 56 + xp) * 64 + c4];
            float4 v10 = *(const float4*)&fb[(yp * 56 + x0) * 64 + c4];
            float4 v11 = *(const float4*)&fb[(yp * 56 + xp) * 64 + c4];
            if (ok) {
                a0 += v00.x * w00 + v01.x * w01 + v10.x * w10 + v11.x * w11;
                a1 += v00.y * w00 + v01.y * w01 + v10.y * w10 + v11.y * w11;
                a2 += v00.z * w00 + v01.z * w01 + v10.z * w10 + v11.z * w11;
                a3 += v00.w * w00 + v01.w * w01 + v10.w * w10 + v11.w * w11;
            }
        }
    }
    ushort4 o;
    o.x = f2bf(a0 * 0.25f);
    o.y = f2bf(a1 * 0.25f);
    o.z = f2bf(a2 * 0.25f);
    o.w = f2bf(a3 * 0.25f);
    *(ushort4*)&roi[(long)rest * 64 + c4] = o;
}

// ---------------------------------------------------------------------------
// fp32 SIMT GEMM (small N: conv3, heads). C = act(A @ W^T + bias)
// ---------------------------------------------------------------------------
__global__ __launch_bounds__(256) void gemm_kernel(const float* __restrict__ A,
    const float* __restrict__ W, const float* __restrict__ bias,
    float* __restrict__ C, int M, int N, int K, int ldw, int relu) {
    __shared__ float As[16][68];
    __shared__ float Ws[16][68];
    const int t = threadIdx.x;
    const int m0 = blockIdx.y * 64, n0 = blockIdx.x * 64;
    const int tx = t & 15, ty = t >> 4;
    const int lm = t >> 2, lk = (t & 3) * 4;
    float acc[4][4] = {};
    for (int k0 = 0; k0 < K; k0 += 16) {
        float4 av = *(const float4*)(A + (long)(m0 + lm) * K + (k0 + lk));
        float4 wv = make_float4(0.f, 0.f, 0.f, 0.f);
        if (n0 + lm < N) wv = *(const float4*)(W + (long)(n0 + lm) * ldw + (k0 + lk));
        As[lk + 0][lm] = av.x; As[lk + 1][lm] = av.y; As[lk + 2][lm] = av.z; As[lk + 3][lm] = av.w;
        Ws[lk + 0][lm] = wv.x; Ws[lk + 1][lm] = wv.y; Ws[lk + 2][lm] = wv.z; Ws[lk + 3][lm] = wv.w;
        __syncthreads();
#pragma unroll
        for (int k = 0; k < 16; ++k) {
            float4 a = *(const float4*)&As[k][ty * 4];
            float4 bv = *(const float4*)&Ws[k][tx * 4];
            acc[0][0] += a.x * bv.x; acc[0][1] += a.x * bv.y; acc[0][2] += a.x * bv.z; acc[0][3] += a.x * bv.w;
            acc[1][0] += a.y * bv.x; acc[1][1] += a.y * bv.y; acc[1][2] += a.y * bv.z; acc[1][3] += a.y * bv.w;
            acc[2][0] += a.z * bv.x; acc[2][1] += a.z * bv.y; acc[2][2] += a.z * bv.z; acc[2][3] += a.z * bv.w;
            acc[3][0] += a.w * bv.x; acc[3][1] += a.w * bv.y; acc[3][2] += a.w * bv.z; acc[3][3] += a.w * bv.w;
        }
        __syncthreads();
    }
#pragma unroll
    for (int i = 0; i < 4; ++i) {
        int m = m0 + ty * 4 + i;
#pragma unroll
        for (int j = 0; j < 4; ++j) {
            int n = n0 + tx * 4 + j;
            if (n < N) {
                float v = acc[i][j] + (bias ? bias[n] : 0.f);
                if (relu) v = fmaxf(v, 0.f);
                C[(long)m * N + n] = v;
            }
        }
    }
}

// ---------------------------------------------------------------------------
// attention dots
// ---------------------------------------------------------------------------
__global__ __launch_bounds__(256) void attn_dots_kernel(const float* __restrict__ h,
    const float* __restrict__ a_s, const float* __restrict__ a_d,
    float* __restrict__ es, float* __restrict__ ed, int heads) {
    int wid = (blockIdx.x * 256 + threadIdx.x) >> 6;
    int lane = threadIdx.x & 63;
    int hd = wid % heads;
    float4 hv = *(const float4*)&h[(long)wid * 256 + lane * 4];
    float4 av = *(const float4*)&a_s[hd * 256 + lane * 4];
    float4 dv = *(const float4*)&a_d[hd * 256 + lane * 4];
    float ps = hv.x * av.x + hv.y * av.y + hv.z * av.z + hv.w * av.w;
    float pd = hv.x * dv.x + hv.y * dv.y + hv.z * dv.z + hv.w * dv.w;
    for (int o = 32; o > 0; o >>= 1) {
        ps += __shfl_down(ps, o, 64);
        pd += __shfl_down(pd, o, 64);
    }
    if (lane == 0) { es[wid] = ps; ed[wid] = pd; }
}

// ---------------------------------------------------------------------------
// CSR build over dst
// ---------------------------------------------------------------------------
__global__ __launch_bounds__(256) void edge_count_kernel(const int* __restrict__ ei,
    int* __restrict__ cnt, int E, int tot) {
    int k = blockIdx.x * 256 + threadIdx.x;
    if (k >= tot) return;
    int d = (k < E) ? ei[E + k] : (k - E);
    atomicAdd(&cnt[d], 1);
}

__global__ __launch_bounds__(1024) void scan_kernel(const int* __restrict__ cnt,
    int* __restrict__ off) {
    __shared__ int sh[1024];
    int t = threadIdx.x;
    int base = t * 4;
    int c0 = cnt[base], c1 = cnt[base + 1], c2 = cnt[base + 2], c3 = cnt[base + 3];
    sh[t] = c0 + c1 + c2 + c3;
    __syncthreads();
    for (int d = 1; d < 1024; d <<= 1) {
        int v = (t >= d) ? sh[t - d] : 0;
        __syncthreads();
        sh[t] += v;
        __syncthreads();
    }
    int excl = (t == 0) ? 0 : sh[t - 1];
    off[base] = excl;
    off[base + 1] = excl + c0;
    off[base + 2] = excl + c0 + c1;
    off[base + 3] = excl + c0 + c1 + c2;
    if (t == 1023) off[4096] = sh[1023];
}

__global__ __launch_bounds__(256) void edge_scatter_kernel(const int* __restrict__ ei,
    const int* __restrict__ off, int* __restrict__ pos, int* __restrict__ eid,
    int E, int tot) {
    int k = blockIdx.x * 256 + threadIdx.x;
    if (k >= tot) return;
    int d = (k < E) ? ei[E + k] : (k - E);
    int p = atomicAdd(&pos[d], 1);
    eid[off[d] + p] = k;
}

// ---------------------------------------------------------------------------
// GAT aggregation. OUTBF: write bf16 (feeds next bgemm) else f32.
// ---------------------------------------------------------------------------
template <int HEADS, int OUTBF>
__global__ __launch_bounds__(256) void gat_aggregate_kernel(const float* __restrict__ h,
    const float* __restrict__ es, const float* __restrict__ ed,
    const int* __restrict__ off, const int* __restrict__ eid,
    const int* __restrict__ ei, const float* __restrict__ bias,
    void* __restrict__ outp, int E) {
    int n = blockIdx.x;
    int t = threadIdx.x;
    int o0 = off[n];
    int deg = off[n + 1] - o0;
    if (deg > 1024) deg = 1024;
    __shared__ float ew[4096];
    __shared__ int   srcs[1024];
    __shared__ float mden[2 * HEADS];
    for (int i = t; i < deg; i += 256) {
        int k = eid[o0 + i];
        int s = (k < E) ? ei[k] : (k - E);
        srcs[i] = s;
#pragma unroll
        for (int hd = 0; hd < HEADS; ++hd) {
            float e = es[s * HEADS + hd] + ed[n * HEADS + hd];
            e = (e >= 0.f) ? e : 0.2f * e;
            ew[i * HEADS + hd] = e;
        }
    }
    __syncthreads();
    if (t < HEADS) {
        float m = -1e30f;
        for (int i = 0; i < deg; ++i) m = fmaxf(m, ew[i * HEADS + t]);
        float den = 0.f;
        for (int i = 0; i < deg; ++i) den += expf(ew[i * HEADS + t] - m);
        mden[t] = m;
        mden[HEADS + t] = den + 1e-16f;
    }
    __syncthreads();
    for (int idx = t; idx < deg * HEADS; idx += 256) {
        int hd = idx % HEADS;
        ew[idx] = expf(ew[idx] - mden[hd]) / mden[HEADS + hd];
    }
    __syncthreads();
    float acc[HEADS];
#pragma unroll
    for (int hd = 0; hd < HEADS; ++hd) acc[hd] = 0.f;
    for (int i = 0; i < deg; ++i) {
        int s = srcs[i];
        const float* hr = &h[(long)s * HEADS * 256];
#pragma unroll
        for (int hd = 0; hd < HEADS; ++hd)
            acc[hd] += ew[i * HEADS + hd] * hr[hd * 256 + t];
    }
#pragma unroll
    for (int hd = 0; hd < HEADS; ++hd) {
        float v = acc[hd] + bias[hd * 256 + t];
        long oi = ((long)n * HEADS + hd) * 256 + t;
        if (OUTBF) ((unsigned short*)outp)[oi] = f2bf(v);
        else       ((float*)outp)[oi] = v;
    }
}

// ---------------------------------------------------------------------------
// rel_logits[e,o] = P1[src_e,o] + P2[dst_e,o] + b_rel[o]
// ---------------------------------------------------------------------------
__global__ __launch_bounds__(256) void rel_scatter_kernel(const float* __restrict__ P1,
    const float* __restrict__ P2, const float* __restrict__ brel,
    const int* __restrict__ ei, float* __restrict__ out, int E) {
    int gi = blockIdx.x * 256 + threadIdx.x;
    int o = gi & 63;
    int e = gi >> 6;
    if (o >= 51 || e >= E) return;
    int s = ei[e], d = ei[E + e];
    out[(long)e * 51 + o] = P1[(long)s * 51 + o] + P2[(long)d * 51 + o] + brel[o];
}

// ---------------------------------------------------------------------------
extern "C" void kernel_launch(void* const* d_in, const int* in_sizes, int n_in,
                              void* d_out, int out_size, void* d_ws, size_t ws_size,
                              hipStream_t stream) {
    const float* images = (const float*)d_in[0];
    const float* boxes  = (const float*)d_in[1];
    const int*   bidx   = (const int*)d_in[2];
    const int*   ei     = (const int*)d_in[3];
    const float* w1     = (const float*)d_in[4];
    const float* g1     = (const float*)d_in[5];
    const float* b1     = (const float*)d_in[6];
    const float* w2     = (const float*)d_in[7];
    const float* g2     = (const float*)d_in[8];
    const float* b2     = (const float*)d_in[9];
    const float* w3     = (const float*)d_in[10];
    const float* g3     = (const float*)d_in[11];
    const float* b3     = (const float*)d_in[12];
    const float* wm1    = (const float*)d_in[13];
    const float* bm1    = (const float*)d_in[14];
    const float* wm2    = (const float*)d_in[15];
    const float* bm2    = (const float*)d_in[16];
    const float* wg1    = (const float*)d_in[17];
    const float* as1    = (const float*)d_in[18];
    const float* ad1    = (const float*)d_in[19];
    const float* bias1  = (const float*)d_in[20];
    const float* wg2    = (const float*)d_in[21];
    const float* as2    = (const float*)d_in[22];
    const float* ad2    = (const float*)d_in[23];
    const float* bias2  = (const float*)d_in[24];
    const float* wobj   = (const float*)d_in[25];
    const float* bobj   = (const float*)d_in[26];
    const float* wrel   = (const float*)d_in[27];
    const float* brel   = (const float*)d_in[28];

    float* ws = (float*)d_ws;
    float* out = (float*)d_out;
    const int E = 65536, TOT = 69632;

    float*  Y1   = ws + Y1_F;
    float*  Y2   = ws + Y2_F;
    float*  Y3N  = ws + Y3N_F;
    float*  Y4N  = ws + Y4N_F;
    float*  Y5N  = ws + Y5N_F;
    float*  Y5T  = ws + Y5T_F;
    float*  HG1  = ws + HG1_F;
    float*  ES1  = ws + ES1_F;
    float*  ED1  = ws + ED1_F;
    float*  HG2  = ws + HG2_F;
    float*  ES2  = ws + ES2_F;
    float*  ED2  = ws + ED2_F;
    float*  O2   = ws + O2_F;
    float*  P1   = ws + P1_F;
    float*  P2   = ws + P2_F;
    unsigned short* Y2BF = (unsigned short*)(ws + Y2BF_F);
    unsigned short* WT2  = (unsigned short*)(ws + WT2_F);
    unsigned short* ROIb = (unsigned short*)(ws + ROI_F);
    unsigned short* WPb  = (unsigned short*)(ws + WP_F);
    unsigned short* H1b  = (unsigned short*)(ws + H1_F);
    unsigned short* H2b  = (unsigned short*)(ws + H2_F);
    unsigned short* O1b  = (unsigned short*)(ws + O1_F);
    unsigned short* WM2b = (unsigned short*)(ws + WM2B_F);
    unsigned short* WG1b = (unsigned short*)(ws + WG1B_F);
    unsigned short* WG2b = (unsigned short*)(ws + WG2B_F);
    double* SD  = (double*)(ws + STATS_F);
    int*    CNT = (int*)(ws + CNT_F);
    int*    POS = (int*)(ws + POS_F);
    int*    OFF = (int*)(ws + OFF_F);
    int*    EID = (int*)(ws + EID_F);

    GaussW gw;
    K5 k5;
    {
        float k1[5];
        float s2 = 2.0f * 0.66f * 0.66f;
        for (int i = 0; i < 5; ++i) {
            float r = (float)i - 2.0f;
            k1[i] = expf(-r * r / s2);
        }
        float tot = 0.f;
        for (int i = 0; i < 5; ++i)
            for (int j = 0; j < 5; ++j) { gw.w[i * 5 + j] = k1[i] * k1[j]; tot += gw.w[i * 5 + j]; }
        for (int i = 0; i < 25; ++i) gw.w[i] /= tot;
        float s1 = 0.f;
        for (int i = 0; i < 5; ++i) s1 += k1[i];
        for (int i = 0; i < 5; ++i) k5.k[i] = k1[i] / s1;   // outer(k5,k5) == gw
    }

    // zero stats (512 f) + CNT (4096 i) + POS (4096 i), contiguous
    hipMemsetAsync((char*)d_ws + STATS_F * 4, 0, (512 + 4096 + 4096) * 4, stream);

    // stage 1 (NCHW fp32)
    conv1_kernel<<<12544, 256, 0, stream>>>(images, w1, Y1);
    bn_stats_kernel<<<dim3(128, 16), 256, 0, stream>>>(Y1, SD, 128, 50176, 8, 4);
    gauss_pool1_sep<<<4 * 128 * 14, 256, 0, stream>>>(Y1, Y2, SD, g1, b1, k5);
    // stage 2 (MFMA implicit GEMM, NHWC)
    nchw2nhwc_bf16<<<784, 256, 0, stream>>>(Y2, Y2BF);
    wt2_kernel<<<1152, 256, 0, stream>>>(w2, WT2);
    conv2_mfma<<<dim3(392, 2), 256, 0, stream>>>(Y2BF, WT2, Y3N);
    bn_stats2_nhwc<<<784, 256, 0, stream>>>(Y3N, SD + 32);
    gauss_pool2_nhwc<<<12544, 256, 0, stream>>>(Y3N, Y4N, SD + 32, g2, b2, gw);
    // stage 3 (1x1 conv == fp32 GEMM on NHWC)
    gemm_kernel<<<dim3(1, 196), 256, 0, stream>>>(Y4N, w3, nullptr, Y5N, 12544, 64, 256, 256, 0);
    bn_stats3_nhwc<<<49, 256, 0, stream>>>(Y5N, SD + 96);
    bnrelu3_nhwc<<<3136, 256, 0, stream>>>(Y5N, Y5T, SD + 96, g3, b3);
    // bf16 weight prep (in dead Y3N region -> must be after gauss_pool2)
    wperm_kernel<<<3136, 256, 0, stream>>>(wm1, WPb);
    castbf_kernel<<<256, 256, 0, stream>>>(wm2, WM2b, 65536);
    castbf_kernel<<<1024, 256, 0, stream>>>(wg1, WG1b, 262144);
    castbf_kernel<<<1024, 256, 0, stream>>>(wg2, WG2b, 262144);
    // ROI align (4 ch/thread) + MLP (bf16 MFMA)
    roi_kernel<<<12544, 256, 0, stream>>>(Y5T, boxes, bidx, ROIb);
    bgemm_kernel<1, 1><<<dim3(32, 2), 256, 0, stream>>>(ROIb, WPb, bm1, nullptr, H1b, 4096, 256, 3136);
    bgemm_kernel<1, 1><<<dim3(32, 2), 256, 0, stream>>>(H1b, WM2b, bm2, nullptr, H2b, 4096, 256, 256);
    // CSR over dst (shared by both GAT layers)
    edge_count_kernel<<<272, 256, 0, stream>>>(ei, CNT, E, TOT);
    scan_kernel<<<1, 1024, 0, stream>>>(CNT, OFF);
    edge_scatter_kernel<<<272, 256, 0, stream>>>(ei, OFF, POS, EID, E, TOT);
    // GAT layer 1 (4 heads, concat)
    bgemm_kernel<0, 0><<<dim3(32, 8), 256, 0, stream>>>(H2b, WG1b, nullptr, HG1, nullptr, 4096, 1024, 256);
    attn_dots_kernel<<<4096, 256, 0, stream>>>(HG1, as1, ad1, ES1, ED1, 4);
    gat_aggregate_kernel<4, 1><<<4096, 256, 0, stream>>>(HG1, ES1, ED1, OFF, EID, ei, bias1, O1b, E);
    // GAT layer 2 (1 head)
    bgemm_kernel<0, 0><<<dim3(32, 2), 256, 0, stream>>>(O1b, WG2b, nullptr, HG2, nullptr, 4096, 256, 1024);
    attn_dots_kernel<<<1024, 256, 0, stream>>>(HG2, as2, ad2, ES2, ED2, 1);
    gat_aggregate_kernel<1, 0><<<4096, 256, 0, stream>>>(HG2, ES2, ED2, OFF, EID, ei, bias2, O2, E);
    // heads (fp32, small N)
    gemm_kernel<<<dim3(3, 64), 256, 0, stream>>>(O2, wobj, bobj, out, 4096, 151, 256, 256, 0);
    gemm_kernel<<<dim3(1, 64), 256, 0, stream>>>(O2, wrel, nullptr, P1, 4096, 51, 256, 512, 0);
    gemm_kernel<<<dim3(1, 64), 256, 0, stream>>>(O2, wrel + 256, nullptr, P2, 4096, 51, 256, 512, 0);
    rel_scatter_kernel<<<16384, 256, 0, stream>>>(P1, P2, brel, ei, out + 618496, E);
}